// Round 21
// baseline (183.939 us; speedup 1.0000x reference)
//
#include <hip/hip_runtime.h>
#include <math.h>

#define N_NODES 32768
#define N_EDGES 524288
#define DIM     128
#define CAP     80

static constexpr size_t NM = (size_t)N_NODES * DIM;   // 4194304

typedef __attribute__((ext_vector_type(8)))  short bf8;     // 8 bf16
typedef __attribute__((ext_vector_type(8)))  unsigned short u16x8;
typedef __attribute__((ext_vector_type(4)))  float f32x4;
typedef __attribute__((ext_vector_type(16))) float f32x16;

__device__ __forceinline__ short f2bs(float x) {
    union { float f; unsigned int u; } v; v.f = x;
    unsigned int r = v.u + 0x7fffu + ((v.u >> 16) & 1u);
    return (short)(r >> 16);
}
__device__ __forceinline__ unsigned int pk2(float a, float b) {
    return (unsigned int)(unsigned short)f2bs(a) |
           ((unsigned int)(unsigned short)f2bs(b) << 16);
}
// truncation pack (P in (0,1]: rel err <= 2^-8, cheap: 3 ops)
__device__ __forceinline__ unsigned int pk2t(float a, float b) {
    union { float f; unsigned int u; } ua, ub; ua.f = a; ub.f = b;
    return (ua.u >> 16) | (ub.u & 0xffff0000u);
}
__device__ __forceinline__ float2 bs2f(unsigned int u) {
    union { unsigned int a; float f; } lo, hi;
    lo.a = u << 16; hi.a = u & 0xffff0000u;
    float2 r; r.x = lo.f; r.y = hi.f; return r;
}
__device__ __forceinline__ float bs1f(short s) {
    union { unsigned int a; float f; } t;
    t.a = ((unsigned int)(unsigned short)s) << 16; return t.f;
}

// ---------------------------------------------------------------------------
// k0: zero deg.
// ---------------------------------------------------------------------------
__global__ __launch_bounds__(256)
void zero_deg_kernel(int4* __restrict__ deg4)
{
    deg4[blockIdx.x * 256 + threadIdx.x] = make_int4(0, 0, 0, 0);  // 8192 int4
}

// ---------------------------------------------------------------------------
// k1: scatter + cvt (R13-proven). blocks [0,2048): slot scatter first;
// [2048,6353): x->bf16, weights->wbf, biases->bcat.
// ---------------------------------------------------------------------------
__global__ __launch_bounds__(256)
void cvt_scatter_kernel(const float* __restrict__ x,
                        const float* __restrict__ w0, const float* __restrict__ w1,
                        const float* __restrict__ w2, const float* __restrict__ w3,
                        const float* __restrict__ w4, const float* __restrict__ w5,
                        const float* __restrict__ w6, const float* __restrict__ w7,
                        const float* __restrict__ w8,
                        const float* __restrict__ b0, const float* __restrict__ b1,
                        const float* __restrict__ b2, const float* __restrict__ b3,
                        const float* __restrict__ b4,
                        const int* __restrict__ ei,
                        short* __restrict__ xb, short* __restrict__ wbf,
                        float* __restrict__ bcat,
                        int* __restrict__ deg, unsigned short* __restrict__ slots)
{
    if (blockIdx.x < 2048) {
        int e = blockIdx.x * 256 + threadIdx.x;            // 0..524287
        int d = ei[N_EDGES + e];
        int pos = atomicAdd(&deg[d], 1);
        if (pos < CAP) slots[d * CAP + pos] = (unsigned short)ei[e];
        return;
    }
    long long t = (long long)(blockIdx.x - 2048) * 256 + threadIdx.x;
    long long i4 = t * 4;
    if (i4 < (long long)NM) {
        float4 v = *(const float4*)(x + i4);
        short4 o; o.x = f2bs(v.x); o.y = f2bs(v.y); o.z = f2bs(v.z); o.w = f2bs(v.w);
        *(short4*)(xb + i4) = o;
    } else {
        int j = (int)(i4 - (long long)NM);
        if (j < 212992) {
            const float* src; int off;
            if      (j <  16384) { src = w0; off = 0; }
            else if (j <  32768) { src = w1; off = 16384; }
            else if (j <  49152) { src = w2; off = 32768; }
            else if (j <  65536) { src = w3; off = 49152; }
            else if (j <  81920) { src = w4; off = 65536; }
            else if (j < 131072) { src = w5; off = 81920; }
            else if (j < 147456) { src = w6; off = 131072; }
            else if (j < 180224) { src = w7; off = 147456; }
            else                 { src = w8; off = 180224; }
            float4 v = *(const float4*)(src + (j - off));
            short4 o; o.x = f2bs(v.x); o.y = f2bs(v.y); o.z = f2bs(v.z); o.w = f2bs(v.w);
            *(short4*)(wbf + j) = o;
        } else if (j < 213632) {
            int jb = j - 212992;                 // 0..639
            int grp = jb >> 7, loc = jb & 127;
            const float* bs = (grp == 0) ? b0 : (grp == 1) ? b1 :
                              (grp == 2) ? b2 : (grp == 3) ? b3 : b4;
            float4 v = *(const float4*)(bs + loc);
            *(float4*)(bcat + jb) = v;
        }
    }
}

// ---------------------------------------------------------------------------
// k2: proj5 MERGED (R16-proven). One block (64 rows), all 5 projections.
// NEW: k and q outputs pre-scaled by log2(e) — gather is their only consumer
// and uses exp2-domain sigmoid.
// ---------------------------------------------------------------------------
__global__ __launch_bounds__(256)
void proj5_kernel(const short* __restrict__ xb, const short* __restrict__ wbf,
                  const float* __restrict__ bcat,
                  short* __restrict__ hin1b, short* __restrict__ kbv,
                  unsigned int* __restrict__ qvu, short* __restrict__ skipb)
{
    const int my = blockIdx.x;            // 0..511
    const int lane = threadIdx.x & 63;
    const int wid  = threadIdx.x >> 6;
    const int m0 = my * 64 + (wid >> 1) * 32;
    const int n0 = (wid & 1) * 64;
    const int lrow = lane & 15;
    const int lk   = (lane >> 4) * 8;
    const float L2E = 1.4426950408889634f;

    bf8 af[2][4];
    const short* Ap = xb + (size_t)(m0 + lrow) * 128 + lk;
    #pragma unroll
    for (int i = 0; i < 2; ++i)
        #pragma unroll
        for (int ks = 0; ks < 4; ++ks)
            af[i][ks] = *(const bf8*)(Ap + (size_t)i * 16 * 128 + ks * 32);

    f32x4 acc[5][2][4] = {};
    #pragma unroll
    for (int ks = 0; ks < 4; ++ks) {
        #pragma unroll
        for (int g = 0; g < 5; ++g) {
            bf8 wf[4];
            const short* Wp = wbf + g * 16384 + (size_t)(n0 + lrow) * 128 + ks * 32 + lk;
            #pragma unroll
            for (int j = 0; j < 4; ++j)
                wf[j] = *(const bf8*)(Wp + (size_t)j * 16 * 128);
            #pragma unroll
            for (int i = 0; i < 2; ++i)
                #pragma unroll
                for (int j = 0; j < 4; ++j)
                    acc[g][i][j] = __builtin_amdgcn_mfma_f32_16x16x32_bf16(
                                       af[i][ks], wf[j], acc[g][i][j], 0, 0, 0);
        }
    }

    const int rbase = (lane >> 4) * 4;
    #pragma unroll
    for (int j = 0; j < 4; ++j) {
        int col = n0 + j * 16 + lrow;                 // 0..127
        float b0c = bcat[col],       b1c = bcat[128 + col];
        float b2c = bcat[256 + col], b3c = bcat[384 + col];
        float b4c = bcat[512 + col];
        #pragma unroll
        for (int i = 0; i < 2; ++i)
            #pragma unroll
            for (int r = 0; r < 4; ++r) {
                int row = m0 + i * 16 + rbase + r;
                size_t ridx = (size_t)row * 128 + col;
                hin1b[ridx] = f2bs(fmaxf(acc[0][i][j][r] + b0c, 0.f));
                kbv[ridx]   = f2bs((acc[1][i][j][r] + b1c) * L2E);   // k*log2e
                qvu[ridx]   = pk2((acc[2][i][j][r] + b2c) * L2E,     // q*log2e
                                  acc[3][i][j][r] + b3c);            // v
                skipb[ridx] = f2bs(acc[4][i][j][r] + b4c);
            }
    }
}

// ---------------------------------------------------------------------------
// k3: in_proj MERGED (R18-proven). One block (64 rows), 3 groups, q pre-scaled.
// ---------------------------------------------------------------------------
__global__ __launch_bounds__(256)
void inproj_kernel(const short* __restrict__ hin1b, const short* __restrict__ wbf,
                   const float* __restrict__ bin, short* __restrict__ qkvb,
                   float qscale)
{
    const int my = blockIdx.x;            // 0..511
    const int lane = threadIdx.x & 63;
    const int wid  = threadIdx.x >> 6;
    const int m0 = my * 64 + (wid >> 1) * 32;
    const int n0 = (wid & 1) * 64;
    const int lrow = lane & 15;
    const int lk   = (lane >> 4) * 8;

    bf8 af[2][4];
    const short* Ap = hin1b + (size_t)(m0 + lrow) * 128 + lk;
    #pragma unroll
    for (int i = 0; i < 2; ++i)
        #pragma unroll
        for (int ks = 0; ks < 4; ++ks)
            af[i][ks] = *(const bf8*)(Ap + (size_t)i * 16 * 128 + ks * 32);

    f32x4 acc[3][2][4] = {};
    #pragma unroll
    for (int ks = 0; ks < 4; ++ks) {
        #pragma unroll
        for (int g = 0; g < 3; ++g) {
            bf8 wf[4];
            const short* Wp = wbf + 81920 + (size_t)(g * 128 + n0 + lrow) * 128
                              + ks * 32 + lk;
            #pragma unroll
            for (int j = 0; j < 4; ++j)
                wf[j] = *(const bf8*)(Wp + (size_t)j * 16 * 128);
            #pragma unroll
            for (int i = 0; i < 2; ++i)
                #pragma unroll
                for (int j = 0; j < 4; ++j)
                    acc[g][i][j] = __builtin_amdgcn_mfma_f32_16x16x32_bf16(
                                       af[i][ks], wf[j], acc[g][i][j], 0, 0, 0);
        }
    }

    const int rbase = (lane >> 4) * 4;
    #pragma unroll
    for (int g = 0; g < 3; ++g) {
        float sc = (g == 0) ? qscale : 1.0f;
        #pragma unroll
        for (int j = 0; j < 4; ++j) {
            int col = g * 128 + n0 + j * 16 + lrow;   // 0..383
            float bcol = bin[col];
            #pragma unroll
            for (int i = 0; i < 2; ++i)
                #pragma unroll
                for (int r = 0; r < 4; ++r) {
                    int row = m0 + i * 16 + rbase + r;
                    float v = (acc[g][i][j][r] + bcol) * sc;
                    qkvb[(size_t)row * 384 + col] = f2bs(v);
                }
        }
    }
}

// ---------------------------------------------------------------------------
// k4: gather via slot lists. One wave/node, 8-edge unroll.
// NEW: exp2-domain sigmoid (k,q pre-scaled by log2e at proj5);
//      vector ushort8 slot loads in the 8-batch.
// ---------------------------------------------------------------------------
__global__ __launch_bounds__(256)
void gather_local_kernel(const unsigned int* __restrict__ kbu,
                         const uint2* __restrict__ qvu,
                         const unsigned int* __restrict__ skipu,
                         const unsigned int* __restrict__ hin1u,
                         const int* __restrict__ deg,
                         const unsigned short* __restrict__ slots,
                         const float* __restrict__ g, const float* __restrict__ beta,
                         unsigned int* __restrict__ hlocal_u)
{
    const int d    = blockIdx.x * 4 + (threadIdx.x >> 6);
    const int lane = threadIdx.x & 63;          // owns cols 2l, 2l+1
    const float rs = 0.9999950000374998f;       // 1/sqrt(1+1e-5)

    float2 k2 = bs2f(kbu[(size_t)d * 64 + lane]);   // pre-scaled by log2e
    int dg = deg[d]; if (dg > CAP) dg = CAP;
    const unsigned short* sp = slots + (size_t)d * CAP;
    int i = 0;

    float ax = 0.f, ay = 0.f, cx = 0.f, cy = 0.f;
    for (; i + 8 <= dg; i += 8) {
        u16x8 sv = *(const u16x8*)(sp + i);     // 16B-aligned (d*160 + i*2)
        uint2 w[8];
        #pragma unroll
        for (int u = 0; u < 8; ++u) w[u] = qvu[(size_t)sv[u] * 64 + lane];
        #pragma unroll
        for (int u = 0; u < 8; ++u) {
            float2 pa = bs2f(w[u].x), pb = bs2f(w[u].y);
            if (u & 1) {
                cx += pa.y * __builtin_amdgcn_rcpf(1.0f + exp2f(-(k2.x + pa.x)));
                cy += pb.y * __builtin_amdgcn_rcpf(1.0f + exp2f(-(k2.y + pb.x)));
            } else {
                ax += pa.y * __builtin_amdgcn_rcpf(1.0f + exp2f(-(k2.x + pa.x)));
                ay += pb.y * __builtin_amdgcn_rcpf(1.0f + exp2f(-(k2.y + pb.x)));
            }
        }
    }
    for (; i + 4 <= dg; i += 4) {
        int s0 = sp[i], s1 = sp[i + 1], s2 = sp[i + 2], s3 = sp[i + 3];
        uint2 w0 = qvu[(size_t)s0 * 64 + lane];
        uint2 w1 = qvu[(size_t)s1 * 64 + lane];
        uint2 w2 = qvu[(size_t)s2 * 64 + lane];
        uint2 w3 = qvu[(size_t)s3 * 64 + lane];
        float2 p0 = bs2f(w0.x), p1 = bs2f(w0.y);
        float2 p2 = bs2f(w1.x), p3 = bs2f(w1.y);
        float2 p4 = bs2f(w2.x), p5 = bs2f(w2.y);
        float2 p6 = bs2f(w3.x), p7 = bs2f(w3.y);
        ax += p0.y * __builtin_amdgcn_rcpf(1.0f + exp2f(-(k2.x + p0.x)));
        ay += p1.y * __builtin_amdgcn_rcpf(1.0f + exp2f(-(k2.y + p1.x)));
        cx += p2.y * __builtin_amdgcn_rcpf(1.0f + exp2f(-(k2.x + p2.x)));
        cy += p3.y * __builtin_amdgcn_rcpf(1.0f + exp2f(-(k2.y + p3.x)));
        ax += p4.y * __builtin_amdgcn_rcpf(1.0f + exp2f(-(k2.x + p4.x)));
        ay += p5.y * __builtin_amdgcn_rcpf(1.0f + exp2f(-(k2.y + p5.x)));
        cx += p6.y * __builtin_amdgcn_rcpf(1.0f + exp2f(-(k2.x + p6.x)));
        cy += p7.y * __builtin_amdgcn_rcpf(1.0f + exp2f(-(k2.y + p7.x)));
    }
    for (; i < dg; ++i) {
        int s0 = sp[i];
        uint2 w0 = qvu[(size_t)s0 * 64 + lane];
        float2 p0 = bs2f(w0.x), p1 = bs2f(w0.y);
        ax += p0.y * __builtin_amdgcn_rcpf(1.0f + exp2f(-(k2.x + p0.x)));
        ay += p1.y * __builtin_amdgcn_rcpf(1.0f + exp2f(-(k2.y + p1.x)));
    }
    ax += cx; ay += cy;

    float2 sk = bs2f(skipu[(size_t)d * 64 + lane]);
    float2 hi = bs2f(hin1u[(size_t)d * 64 + lane]);
    float2 gv = *(const float2*)(g + lane * 2);
    float2 bt = *(const float2*)(beta + lane * 2);
    float ox = (hi.x + sk.x + ax) * (gv.x * rs) + bt.x;
    float oy = (hi.y + sk.y + ay) * (gv.y * rs) + bt.y;
    hlocal_u[(size_t)d * 64 + lane] = pk2(ox, oy);
}

// ---------------------------------------------------------------------------
// k5: MFMA flash attention (R16-proven). 512 blocks = (b,h,half), 512 thr
// (8 waves, 32 q-rows each). Chunked dbuf K/V staging; exp2 softmax;
// truncation P-pack.
// ---------------------------------------------------------------------------
__device__ __forceinline__ void lswap(unsigned int& X, unsigned int& Y, bool hi) {
    unsigned int Xs = (unsigned int)__shfl_xor((int)X, 32);
    unsigned int Ys = (unsigned int)__shfl_xor((int)Y, 32);
    unsigned int Xn = hi ? Ys : X;
    unsigned int Yn = hi ? Y  : Xs;
    X = Xn; Y = Yn;
}

__global__ __launch_bounds__(512)
void attn_mfma(const short* __restrict__ qkv, short* __restrict__ ctx)
{
    __shared__ __align__(16) char lds[36864];
    // carve: K buf s at lds + s*10240 (128 keys x 40 shorts);
    //        V^T buf s at lds + 20480 + s*8192 (32 rows x 256 B, swizzled)

    const int blk  = blockIdx.x;         // B*H*2 = 512
    const int half = blk & 1;
    const int h    = (blk >> 1) & 3;
    const int b    = blk >> 3;
    const int tid  = threadIdx.x;        // 0..511
    const int lane = tid & 63;
    const int wid  = tid >> 6;           // 0..7
    const int lq = lane & 31;
    const int lg = lane >> 5;
    const size_t gbase = (size_t)(b * 512) * 384 + h * 32;

    const int skey  = tid >> 2;          // 0..127
    const int spart = tid & 3;
    const int vp    = tid & 63;
    const int vdq   = tid >> 6;

    bf8    kst;
    short4 v0s, v1s;

    #define STAGE_LOAD(ck)                                                     \
        kst = *(const bf8*)(qkv + gbase +                                      \
                (size_t)((ck) * 128 + skey) * 384 + 128 + spart * 8);          \
        {                                                                      \
            const short* vr = qkv + gbase +                                    \
                (size_t)((ck) * 128 + 2 * vp) * 384 + 256 + vdq * 4;           \
            v0s = *(const short4*)(vr);                                        \
            v1s = *(const short4*)(vr + 384);                                  \
        }

    #define STAGE_WRITE(s)                                                     \
        *(bf8*)((short*)(lds + (s) * 10240) + skey * 40 + spart * 8) = kst;    \
        {                                                                      \
            char* vb = lds + 20480 + (s) * 8192;                               \
            short v0a[4] = {v0s.x, v0s.y, v0s.z, v0s.w};                       \
            short v1a[4] = {v1s.x, v1s.y, v1s.z, v1s.w};                       \
            _Pragma("unroll")                                                  \
            for (int j = 0; j < 4; ++j) {                                      \
                int d = vdq * 4 + j;                                           \
                unsigned int w = (unsigned int)(unsigned short)v0a[j] |        \
                                 ((unsigned int)(unsigned short)v1a[j] << 16); \
                *(unsigned int*)(vb + d * 256 + ((4 * vp) ^ ((d & 7) << 4))) = w; \
            }                                                                  \
        }

    const int qoff = half * 256 + wid * 32;
    bf8 qf[2];
    #pragma unroll
    for (int kh = 0; kh < 2; ++kh)
        qf[kh] = *(const bf8*)(qkv + gbase +
                       (size_t)(qoff + lq) * 384 + kh * 16 + lg * 8);

    const f32x16 Z16 = {0.f,0.f,0.f,0.f,0.f,0.f,0.f,0.f,0.f,0.f,0.f,0.f,0.f,0.f,0.f,0.f};
    f32x16 o = Z16;
    float mreg = -1e30f;
    float lreg = 0.f;
    const bool hiw = (lg != 0);

    STAGE_LOAD(0);
    STAGE_WRITE(0);
    __syncthreads();

    for (int c = 0; c < 4; ++c) {
        if (c < 3) { STAGE_LOAD(c + 1); }
        const short* Kb = (const short*)(lds + (c & 1) * 10240);
        const char*  Vb = lds + 20480 + (c & 1) * 8192;

        #pragma unroll
        for (int ktl = 0; ktl < 4; ++ktl) {
            bf8 ak[2], vt[2];
            #pragma unroll
            for (int kh = 0; kh < 2; ++kh) {
                ak[kh] = *(const bf8*)(Kb + (ktl * 32 + lq) * 40 + kh * 16 + lg * 8);
                int kbyte = (ktl * 32 + kh * 16 + lg * 8) * 2;   // 0..254
                vt[kh] = *(const bf8*)(Vb + lq * 256 + (kbyte ^ ((lq & 7) << 4)));
            }
            f32x16 s = Z16;
            s = __builtin_amdgcn_mfma_f32_32x32x16_bf16(ak[0], qf[0], s, 0, 0, 0);
            s = __builtin_amdgcn_mfma_f32_32x32x16_bf16(ak[1], qf[1], s, 0, 0, 0);
            float t0 = fmaxf(fmaxf(s[0],  s[1]),  s[2]);
            float t1 = fmaxf(fmaxf(s[3],  s[4]),  s[5]);
            float t2 = fmaxf(fmaxf(s[6],  s[7]),  s[8]);
            float t3 = fmaxf(fmaxf(s[9],  s[10]), s[11]);
            float t4 = fmaxf(fmaxf(s[12], s[13]), s[14]);
            float mt = fmaxf(fmaxf(fmaxf(t0, t1), t2), fmaxf(fmaxf(t3, t4), s[15]));
            mt = fmaxf(mt, __shfl_xor(mt, 32));
            if (__any(mt > mreg + 11.5415603f)) {    // defer-max, log2 domain
                float mnew = fmaxf(mreg, mt);
                float corr = exp2f(mreg - mnew);
                mreg = mnew;
                lreg *= corr;
                #pragma unroll
                for (int r = 0; r < 16; ++r) o[r] *= corr;
            }
            float m = mreg;
            float p[16]; float ps = 0.f;
            #pragma unroll
            for (int r = 0; r < 16; ++r) { p[r] = exp2f(s[r] - m); ps += p[r]; }
            ps += __shfl_xor(ps, 32);
            lreg += ps;
            unsigned int w0 = pk2t(p[0],  p[1]),  w1 = pk2t(p[2],  p[3]);
            unsigned int w2 = pk2t(p[4],  p[5]),  w3 = pk2t(p[6],  p[7]);
            unsigned int w4 = pk2t(p[8],  p[9]),  w5 = pk2t(p[10], p[11]);
            unsigned int w6 = pk2t(p[12], p[13]), w7 = pk2t(p[14], p[15]);
            lswap(w0, w2, hiw); lswap(w1, w3, hiw);
            lswap(w4, w6, hiw); lswap(w5, w7, hiw);
            union { unsigned int u[4]; bf8 v; } P0, P1;
            P0.u[0] = w0; P0.u[1] = w1; P0.u[2] = w2; P0.u[3] = w3;
            P1.u[0] = w4; P1.u[1] = w5; P1.u[2] = w6; P1.u[3] = w7;
            o = __builtin_amdgcn_mfma_f32_32x32x16_bf16(vt[0], P0.v, o, 0, 0, 0);
            o = __builtin_amdgcn_mfma_f32_32x32x16_bf16(vt[1], P1.v, o, 0, 0, 0);
        }
        if (c < 3) { STAGE_WRITE((c + 1) & 1); }
        __syncthreads();
    }
    #undef STAGE_LOAD
    #undef STAGE_WRITE

    // epilogue: O^T regs -> LDS (swizzled, 16 KB) -> coalesced global
    {
        float inv = 1.0f / lreg;
        int ql = wid * 32 + lq;            // 0..255 (block-local q)
        #pragma unroll
        for (int b4 = 0; b4 < 4; ++b4) {
            short4 pkv;
            pkv.x = f2bs(o[b4 * 4 + 0] * inv);
            pkv.y = f2bs(o[b4 * 4 + 1] * inv);
            pkv.z = f2bs(o[b4 * 4 + 2] * inv);
            pkv.w = f2bs(o[b4 * 4 + 3] * inv);
            int dbyte = (8 * b4 + 4 * lg) * 2;
            *(short4*)(lds + ql * 64 + (dbyte ^ ((ql & 7) << 3))) = pkv;
        }
    }
    __syncthreads();
    {
        int row  = tid >> 1;                // 0..255
        int pbase = (tid & 1) * 4;          // 0 or 4
        short* dst = ctx + (size_t)(b * 512 + half * 256 + row) * 128 + h * 32;
        #pragma unroll
        for (int i = 0; i < 4; ++i) {
            int part = pbase + i;           // 0..7
            short4 pv = *(short4*)(lds + row * 64 + ((part * 8) ^ ((row & 7) << 3)));
            *(short4*)(dst + part * 4) = pv;
        }
    }
}

// ---------------------------------------------------------------------------
// k6: FUSED out_proj+combine+FFN+finalBN (R11-proven). 512 blocks.
// ---------------------------------------------------------------------------
__global__ __launch_bounds__(256)
void outproj_ff_kernel(const short* __restrict__ ctxb, const short* __restrict__ wbf,
                       const float* __restrict__ bout,
                       const short* __restrict__ hin1b, const short* __restrict__ hlocb,
                       const float* __restrict__ g1a, const float* __restrict__ b1a,
                       const float* __restrict__ b1, const float* __restrict__ b2,
                       const float* __restrict__ g2, const float* __restrict__ b2g,
                       float* __restrict__ out)
{
    __shared__ __align__(16) short ldsH[64 * 128];   // 16 KB, byte ^ ((row&7)<<4)
    __shared__ __align__(16) short ldsF[64 * 256];   // 32 KB, byte ^ ((row&7)<<4)
    const int my = blockIdx.x;
    const int lane = threadIdx.x & 63;
    const int wid  = threadIdx.x >> 6;
    const int lrow = lane & 15;
    const int lk   = (lane >> 4) * 8;
    const int rbase = (lane >> 4) * 4;
    const float rs = 0.9999950000374998f;

    // ---- phase 0: out_proj + combine -> ldsH ----
    {
        const int m0 = (wid >> 1) * 32;
        const int n0 = (wid & 1) * 64;
        f32x4 acc[2][4] = {};
        const short* Ap = ctxb + (size_t)(my * 64 + m0 + lrow) * 128 + lk;
        const short* Wp = wbf + 131072 + (size_t)(n0 + lrow) * 128 + lk;
        #pragma unroll
        for (int ks = 0; ks < 128; ks += 32) {
            bf8 af[2], wf[4];
            af[0] = *(const bf8*)(Ap + ks);
            af[1] = *(const bf8*)(Ap + 16 * 128 + ks);
            #pragma unroll
            for (int j = 0; j < 4; ++j) wf[j] = *(const bf8*)(Wp + (size_t)j * 16 * 128 + ks);
            #pragma unroll
            for (int i = 0; i < 2; ++i)
                #pragma unroll
                for (int j = 0; j < 4; ++j)
                    acc[i][j] = __builtin_amdgcn_mfma_f32_16x16x32_bf16(af[i], wf[j], acc[i][j], 0, 0, 0);
        }
        #pragma unroll
        for (int j = 0; j < 4; ++j) {
            int col = n0 + j * 16 + lrow;            // 0..127
            float bcol = bout[col];
            float gsc = g1a[col] * rs;
            float bsc = b1a[col];
            #pragma unroll
            for (int i = 0; i < 2; ++i)
                #pragma unroll
                for (int r = 0; r < 4; ++r) {
                    int rl = m0 + i * 16 + rbase + r;
                    size_t idx = (size_t)(my * 64 + rl) * 128 + col;
                    float v = acc[i][j][r] + bcol;
                    float o = bs1f(hlocb[idx]) + (bs1f(hin1b[idx]) + v) * gsc + bsc;
                    int byte = (rl * 256 + col * 2) ^ ((rl & 7) << 4);
                    *(short*)((char*)ldsH + byte) = f2bs(o);
                }
        }
    }
    __syncthreads();
    // ---- phase 1: ff1 -> ldsF ----
    {
        const int m0 = (wid >> 1) * 32;
        const int n0 = (wid & 1) * 128;
        f32x4 acc[2][8] = {};
        const short* Wp = wbf + 147456 + (size_t)(n0 + lrow) * 128 + lk;
        #pragma unroll
        for (int ks = 0; ks < 128; ks += 32) {
            bf8 af[2], wf[8];
            #pragma unroll
            for (int i = 0; i < 2; ++i) {
                int row = m0 + lrow + i * 16;
                int byte = (row * 256 + (ks + lk) * 2) ^ ((row & 7) << 4);
                af[i] = *(const bf8*)((const char*)ldsH + byte);
            }
            #pragma unroll
            for (int j = 0; j < 8; ++j) wf[j] = *(const bf8*)(Wp + (size_t)j * 16 * 128 + ks);
            #pragma unroll
            for (int i = 0; i < 2; ++i)
                #pragma unroll
                for (int j = 0; j < 8; ++j)
                    acc[i][j] = __builtin_amdgcn_mfma_f32_16x16x32_bf16(af[i], wf[j], acc[i][j], 0, 0, 0);
        }
        #pragma unroll
        for (int j = 0; j < 8; ++j) {
            int col = n0 + j * 16 + lrow;            // 0..255
            float bc = b1[col];
            #pragma unroll
            for (int i = 0; i < 2; ++i)
                #pragma unroll
                for (int r = 0; r < 4; ++r) {
                    int rl = m0 + i * 16 + rbase + r;
                    float v = fmaxf(acc[i][j][r] + bc, 0.f);
                    int byte = (rl * 512 + col * 2) ^ ((rl & 7) << 4);
                    *(short*)((char*)ldsF + byte) = f2bs(v);
                }
        }
    }
    __syncthreads();
    // ---- phase 2: ff2 + final BN (residual from ldsH) ----
    {
        const int m0 = (wid >> 1) * 32;
        const int n0 = (wid & 1) * 64;
        f32x4 acc[2][4] = {};
        const short* Wp = wbf + 180224 + (size_t)(n0 + lrow) * 256 + lk;
        #pragma unroll
        for (int ks = 0; ks < 256; ks += 32) {
            bf8 af[2], wf[4];
            #pragma unroll
            for (int i = 0; i < 2; ++i) {
                int row = m0 + lrow + i * 16;
                int byte = (row * 512 + (ks + lk) * 2) ^ ((row & 7) << 4);
                af[i] = *(const bf8*)((const char*)ldsF + byte);
            }
            #pragma unroll
            for (int j = 0; j < 4; ++j) wf[j] = *(const bf8*)(Wp + (size_t)j * 16 * 256 + ks);
            #pragma unroll
            for (int i = 0; i < 2; ++i)
                #pragma unroll
                for (int j = 0; j < 4; ++j)
                    acc[i][j] = __builtin_amdgcn_mfma_f32_16x16x32_bf16(af[i], wf[j], acc[i][j], 0, 0, 0);
        }
        #pragma unroll
        for (int j = 0; j < 4; ++j) {
            int col = n0 + j * 16 + lrow;
            float bc = b2[col];
            float gsc = g2[col] * rs;
            float bsc = b2g[col];
            #pragma unroll
            for (int i = 0; i < 2; ++i)
                #pragma unroll
                for (int r = 0; r < 4; ++r) {
                    int rl = m0 + i * 16 + rbase + r;
                    int hbyte = (rl * 256 + col * 2) ^ ((rl & 7) << 4);
                    float hres = bs1f(*(const short*)((const char*)ldsH + hbyte));
                    float v = acc[i][j][r] + bc;
                    out[(size_t)(my * 64 + rl) * 128 + col] = (hres + v) * gsc + bsc;
                }
        }
    }
}

// ---------------------------------------------------------------------------
extern "C" void kernel_launch(void* const* d_in, const int* in_sizes, int n_in,
                              void* d_out, int out_size, void* d_ws, size_t ws_size,
                              hipStream_t stream)
{
    (void)in_sizes; (void)n_in; (void)out_size; (void)ws_size;

    const float* x    = (const float*)d_in[0];
    const int*   ei   = (const int*)d_in[1];
    const float* Wres = (const float*)d_in[3];
    const float* bres = (const float*)d_in[4];
    const float* Wk   = (const float*)d_in[5];
    const float* bk   = (const float*)d_in[6];
    const float* Wq   = (const float*)d_in[7];
    const float* bq   = (const float*)d_in[8];
    const float* Wv   = (const float*)d_in[9];
    const float* bv   = (const float*)d_in[10];
    const float* Wsk  = (const float*)d_in[11];
    const float* bsk  = (const float*)d_in[12];
    const float* g1l  = (const float*)d_in[13];
    const float* b1l  = (const float*)d_in[14];
    const float* g1a  = (const float*)d_in[15];
    const float* b1a  = (const float*)d_in[16];
    const float* Win  = (const float*)d_in[17];
    const float* bin  = (const float*)d_in[18];
    const float* Wout = (const float*)d_in[19];
    const float* bout = (const float*)d_in[20];
    const float* W1   = (const float*)d_in[21];
    const float* b1   = (const float*)d_in[22];
    const float* W2   = (const float*)d_in[23];
    const float* b2   = (const float*)d_in[24];
    const float* g2   = (const float*)d_in[25];
    const float* b2g  = (const float*)d_in[26];
    float* out = (float*)d_out;

    float* ws = (float*)d_ws;
    // ----- workspace layout (float-slot offsets), lifetimes k0..k6 -----
    short* hin1b = (short*)ws;                        // [0,0.5NM)  w:k2 r:k3,k4,k6
    short* kbv   = (short*)(ws + NM / 2);             // [0.5NM,NM) w:k2 r:k4
    short* qvb   = (short*)(ws + NM);                 // [NM,2NM)   w:k2 r:k4 (q,v ilv)
    short* skipb = (short*)(ws + 2 * NM);             // [2NM,2.5NM) w:k2 r:k4
    short* xb    = (short*)(ws + 2 * NM + NM / 2);    // [2.5NM,3NM) w:k1 r:k2
    short* qkvb  = (short*)(ws + 3 * NM);             // [3NM,4.5NM) w:k3 r:k5
    short* hlocb = (short*)(ws + 4 * NM + NM / 2);    // [4.5NM,5NM) w:k4 r:k6
    // slot ints/ushorts overlay [5NM, ...) — dead after k4; ctxb (w:k5) reuses it
    int* deg = (int*)(ws + 5 * NM);                   // [N] w:k0, rmw:k1 r:k4
    unsigned short* slots = (unsigned short*)(deg + N_NODES);  // [N*CAP] w:k1 r:k4
    short* ctxb  = (short*)(ws + 5 * NM);             // [5NM,5.5NM) w:k5 r:k6
    short* wbf   = (short*)(ws + 6 * NM);             // 212992 shorts = 106496 fslots
    float* bcat  = ws + 6 * NM + 106496;              // [640] f32
    // total extent: 6NM + 107136 floats ≈ 101.1 MB

    dim3 blk(256);
    // 1/sqrt(32) * log2(e)  (exp2-domain softmax)
    const float qscale = 0.17677669529663687f * 1.4426950408889634f;

    // 0. zero deg
    zero_deg_kernel<<<dim3(32), blk, 0, stream>>>((int4*)deg);

    // 1. scatter (first) + cvt
    cvt_scatter_kernel<<<dim3(6353), blk, 0, stream>>>(
        x, Wres, Wk, Wq, Wv, Wsk, Win, Wout, W1, W2,
        bres, bk, bq, bv, bsk, ei, xb, wbf, bcat, deg, slots);

    // 2. proj5 GEMM (merged 5 groups; k,q pre-scaled by log2e)
    proj5_kernel<<<dim3(512), blk, 0, stream>>>(
        xb, wbf, bcat, hin1b, kbv, (unsigned int*)qvb, skipb);

    // 3. in_proj GEMM (merged 3 groups)
    inproj_kernel<<<dim3(512), blk, 0, stream>>>(
        hin1b, wbf, bin, qkvb, qscale);

    // 4. gather + skip + BN (slot lists; exp2 sigmoid; vector slot loads)
    gather_local_kernel<<<dim3(N_NODES / 4), blk, 0, stream>>>(
        (const unsigned int*)kbv, (const uint2*)qvb, (const unsigned int*)skipb,
        (const unsigned int*)hin1b, deg, slots, g1l, b1l,
        (unsigned int*)hlocb);

    // 5. attention (512 blocks x 512 thr, 2 blocks/CU; trunc P-pack)
    attn_mfma<<<dim3(512), dim3(512), 0, stream>>>(qkvb, ctxb);

    // 6. fused out_proj + combine + FFN + final BN
    outproj_ff_kernel<<<dim3(512), blk, 0, stream>>>(
        ctxb, wbf, bout, hin1b, hlocb, g1a, b1a, b1, b2, g2, b2g, out);
}

// Round 22
// 183.600 us; speedup vs baseline: 1.0018x; 1.0018x over previous
//
#include <hip/hip_runtime.h>
#include <math.h>

#define N_NODES 32768
#define N_EDGES 524288
#define DIM     128
#define CAP     80

static constexpr size_t NM = (size_t)N_NODES * DIM;   // 4194304

typedef __attribute__((ext_vector_type(8)))  short bf8;     // 8 bf16
typedef __attribute__((ext_vector_type(8)))  unsigned short u16x8;
typedef __attribute__((ext_vector_type(4)))  float f32x4;
typedef __attribute__((ext_vector_type(16))) float f32x16;

__device__ __forceinline__ short f2bs(float x) {
    union { float f; unsigned int u; } v; v.f = x;
    unsigned int r = v.u + 0x7fffu + ((v.u >> 16) & 1u);
    return (short)(r >> 16);
}
__device__ __forceinline__ unsigned int pk2(float a, float b) {
    return (unsigned int)(unsigned short)f2bs(a) |
           ((unsigned int)(unsigned short)f2bs(b) << 16);
}
// truncation pack (P in (0,1]: rel err <= 2^-8, cheap: 3 ops)
__device__ __forceinline__ unsigned int pk2t(float a, float b) {
    union { float f; unsigned int u; } ua, ub; ua.f = a; ub.f = b;
    return (ua.u >> 16) | (ub.u & 0xffff0000u);
}
__device__ __forceinline__ float2 bs2f(unsigned int u) {
    union { unsigned int a; float f; } lo, hi;
    lo.a = u << 16; hi.a = u & 0xffff0000u;
    float2 r; r.x = lo.f; r.y = hi.f; return r;
}
__device__ __forceinline__ float bs1f(short s) {
    union { unsigned int a; float f; } t;
    t.a = ((unsigned int)(unsigned short)s) << 16; return t.f;
}

// ---------------------------------------------------------------------------
// k0: zero deg.
// ---------------------------------------------------------------------------
__global__ __launch_bounds__(256)
void zero_deg_kernel(int4* __restrict__ deg4)
{
    deg4[blockIdx.x * 256 + threadIdx.x] = make_int4(0, 0, 0, 0);  // 8192 int4
}

// ---------------------------------------------------------------------------
// k1: scatter + cvt (R13-proven). blocks [0,2048): slot scatter first;
// [2048,6353): x->bf16, weights->wbf, biases->bcat.
// ---------------------------------------------------------------------------
__global__ __launch_bounds__(256)
void cvt_scatter_kernel(const float* __restrict__ x,
                        const float* __restrict__ w0, const float* __restrict__ w1,
                        const float* __restrict__ w2, const float* __restrict__ w3,
                        const float* __restrict__ w4, const float* __restrict__ w5,
                        const float* __restrict__ w6, const float* __restrict__ w7,
                        const float* __restrict__ w8,
                        const float* __restrict__ b0, const float* __restrict__ b1,
                        const float* __restrict__ b2, const float* __restrict__ b3,
                        const float* __restrict__ b4,
                        const int* __restrict__ ei,
                        short* __restrict__ xb, short* __restrict__ wbf,
                        float* __restrict__ bcat,
                        int* __restrict__ deg, unsigned short* __restrict__ slots)
{
    if (blockIdx.x < 2048) {
        int e = blockIdx.x * 256 + threadIdx.x;            // 0..524287
        int d = ei[N_EDGES + e];
        int pos = atomicAdd(&deg[d], 1);
        if (pos < CAP) slots[d * CAP + pos] = (unsigned short)ei[e];
        return;
    }
    long long t = (long long)(blockIdx.x - 2048) * 256 + threadIdx.x;
    long long i4 = t * 4;
    if (i4 < (long long)NM) {
        float4 v = *(const float4*)(x + i4);
        short4 o; o.x = f2bs(v.x); o.y = f2bs(v.y); o.z = f2bs(v.z); o.w = f2bs(v.w);
        *(short4*)(xb + i4) = o;
    } else {
        int j = (int)(i4 - (long long)NM);
        if (j < 212992) {
            const float* src; int off;
            if      (j <  16384) { src = w0; off = 0; }
            else if (j <  32768) { src = w1; off = 16384; }
            else if (j <  49152) { src = w2; off = 32768; }
            else if (j <  65536) { src = w3; off = 49152; }
            else if (j <  81920) { src = w4; off = 65536; }
            else if (j < 131072) { src = w5; off = 81920; }
            else if (j < 147456) { src = w6; off = 131072; }
            else if (j < 180224) { src = w7; off = 147456; }
            else                 { src = w8; off = 180224; }
            float4 v = *(const float4*)(src + (j - off));
            short4 o; o.x = f2bs(v.x); o.y = f2bs(v.y); o.z = f2bs(v.z); o.w = f2bs(v.w);
            *(short4*)(wbf + j) = o;
        } else if (j < 213632) {
            int jb = j - 212992;                 // 0..639
            int grp = jb >> 7, loc = jb & 127;
            const float* bs = (grp == 0) ? b0 : (grp == 1) ? b1 :
                              (grp == 2) ? b2 : (grp == 3) ? b3 : b4;
            float4 v = *(const float4*)(bs + loc);
            *(float4*)(bcat + jb) = v;
        }
    }
}

// ---------------------------------------------------------------------------
// k2: proj5 MERGED (R16-proven). One block (64 rows), all 5 projections.
// NEW: k and q outputs pre-scaled by log2(e) — gather is their only consumer
// and uses exp2-domain sigmoid.
// ---------------------------------------------------------------------------
__global__ __launch_bounds__(256)
void proj5_kernel(const short* __restrict__ xb, const short* __restrict__ wbf,
                  const float* __restrict__ bcat,
                  short* __restrict__ hin1b, short* __restrict__ kbv,
                  unsigned int* __restrict__ qvu, short* __restrict__ skipb)
{
    const int my = blockIdx.x;            // 0..511
    const int lane = threadIdx.x & 63;
    const int wid  = threadIdx.x >> 6;
    const int m0 = my * 64 + (wid >> 1) * 32;
    const int n0 = (wid & 1) * 64;
    const int lrow = lane & 15;
    const int lk   = (lane >> 4) * 8;
    const float L2E = 1.4426950408889634f;

    bf8 af[2][4];
    const short* Ap = xb + (size_t)(m0 + lrow) * 128 + lk;
    #pragma unroll
    for (int i = 0; i < 2; ++i)
        #pragma unroll
        for (int ks = 0; ks < 4; ++ks)
            af[i][ks] = *(const bf8*)(Ap + (size_t)i * 16 * 128 + ks * 32);

    f32x4 acc[5][2][4] = {};
    #pragma unroll
    for (int ks = 0; ks < 4; ++ks) {
        #pragma unroll
        for (int g = 0; g < 5; ++g) {
            bf8 wf[4];
            const short* Wp = wbf + g * 16384 + (size_t)(n0 + lrow) * 128 + ks * 32 + lk;
            #pragma unroll
            for (int j = 0; j < 4; ++j)
                wf[j] = *(const bf8*)(Wp + (size_t)j * 16 * 128);
            #pragma unroll
            for (int i = 0; i < 2; ++i)
                #pragma unroll
                for (int j = 0; j < 4; ++j)
                    acc[g][i][j] = __builtin_amdgcn_mfma_f32_16x16x32_bf16(
                                       af[i][ks], wf[j], acc[g][i][j], 0, 0, 0);
        }
    }

    const int rbase = (lane >> 4) * 4;
    #pragma unroll
    for (int j = 0; j < 4; ++j) {
        int col = n0 + j * 16 + lrow;                 // 0..127
        float b0c = bcat[col],       b1c = bcat[128 + col];
        float b2c = bcat[256 + col], b3c = bcat[384 + col];
        float b4c = bcat[512 + col];
        #pragma unroll
        for (int i = 0; i < 2; ++i)
            #pragma unroll
            for (int r = 0; r < 4; ++r) {
                int row = m0 + i * 16 + rbase + r;
                size_t ridx = (size_t)row * 128 + col;
                hin1b[ridx] = f2bs(fmaxf(acc[0][i][j][r] + b0c, 0.f));
                kbv[ridx]   = f2bs((acc[1][i][j][r] + b1c) * L2E);   // k*log2e
                qvu[ridx]   = pk2((acc[2][i][j][r] + b2c) * L2E,     // q*log2e
                                  acc[3][i][j][r] + b3c);            // v
                skipb[ridx] = f2bs(acc[4][i][j][r] + b4c);
            }
    }
}

// ---------------------------------------------------------------------------
// k3: in_proj MERGED (R18-proven). One block (64 rows), 3 groups, q pre-scaled.
// ---------------------------------------------------------------------------
__global__ __launch_bounds__(256)
void inproj_kernel(const short* __restrict__ hin1b, const short* __restrict__ wbf,
                   const float* __restrict__ bin, short* __restrict__ qkvb,
                   float qscale)
{
    const int my = blockIdx.x;            // 0..511
    const int lane = threadIdx.x & 63;
    const int wid  = threadIdx.x >> 6;
    const int m0 = my * 64 + (wid >> 1) * 32;
    const int n0 = (wid & 1) * 64;
    const int lrow = lane & 15;
    const int lk   = (lane >> 4) * 8;

    bf8 af[2][4];
    const short* Ap = hin1b + (size_t)(m0 + lrow) * 128 + lk;
    #pragma unroll
    for (int i = 0; i < 2; ++i)
        #pragma unroll
        for (int ks = 0; ks < 4; ++ks)
            af[i][ks] = *(const bf8*)(Ap + (size_t)i * 16 * 128 + ks * 32);

    f32x4 acc[3][2][4] = {};
    #pragma unroll
    for (int ks = 0; ks < 4; ++ks) {
        #pragma unroll
        for (int g = 0; g < 3; ++g) {
            bf8 wf[4];
            const short* Wp = wbf + 81920 + (size_t)(g * 128 + n0 + lrow) * 128
                              + ks * 32 + lk;
            #pragma unroll
            for (int j = 0; j < 4; ++j)
                wf[j] = *(const bf8*)(Wp + (size_t)j * 16 * 128);
            #pragma unroll
            for (int i = 0; i < 2; ++i)
                #pragma unroll
                for (int j = 0; j < 4; ++j)
                    acc[g][i][j] = __builtin_amdgcn_mfma_f32_16x16x32_bf16(
                                       af[i][ks], wf[j], acc[g][i][j], 0, 0, 0);
        }
    }

    const int rbase = (lane >> 4) * 4;
    #pragma unroll
    for (int g = 0; g < 3; ++g) {
        float sc = (g == 0) ? qscale : 1.0f;
        #pragma unroll
        for (int j = 0; j < 4; ++j) {
            int col = g * 128 + n0 + j * 16 + lrow;   // 0..383
            float bcol = bin[col];
            #pragma unroll
            for (int i = 0; i < 2; ++i)
                #pragma unroll
                for (int r = 0; r < 4; ++r) {
                    int row = m0 + i * 16 + rbase + r;
                    float v = (acc[g][i][j][r] + bcol) * sc;
                    qkvb[(size_t)row * 384 + col] = f2bs(v);
                }
        }
    }
}

// ---------------------------------------------------------------------------
// k4: gather via slot lists. One wave/node, 8-edge unroll.
// NEW: exp2-domain sigmoid (k,q pre-scaled by log2e at proj5);
//      vector ushort8 slot loads in the 8-batch.
// ---------------------------------------------------------------------------
__global__ __launch_bounds__(256)
void gather_local_kernel(const unsigned int* __restrict__ kbu,
                         const uint2* __restrict__ qvu,
                         const unsigned int* __restrict__ skipu,
                         const unsigned int* __restrict__ hin1u,
                         const int* __restrict__ deg,
                         const unsigned short* __restrict__ slots,
                         const float* __restrict__ g, const float* __restrict__ beta,
                         unsigned int* __restrict__ hlocal_u)
{
    const int d    = blockIdx.x * 4 + (threadIdx.x >> 6);
    const int lane = threadIdx.x & 63;          // owns cols 2l, 2l+1
    const float rs = 0.9999950000374998f;       // 1/sqrt(1+1e-5)

    float2 k2 = bs2f(kbu[(size_t)d * 64 + lane]);   // pre-scaled by log2e
    int dg = deg[d]; if (dg > CAP) dg = CAP;
    const unsigned short* sp = slots + (size_t)d * CAP;
    int i = 0;

    float ax = 0.f, ay = 0.f, cx = 0.f, cy = 0.f;
    for (; i + 8 <= dg; i += 8) {
        u16x8 sv = *(const u16x8*)(sp + i);     // 16B-aligned (d*160 + i*2)
        uint2 w[8];
        #pragma unroll
        for (int u = 0; u < 8; ++u) w[u] = qvu[(size_t)sv[u] * 64 + lane];
        #pragma unroll
        for (int u = 0; u < 8; ++u) {
            float2 pa = bs2f(w[u].x), pb = bs2f(w[u].y);
            if (u & 1) {
                cx += pa.y * __builtin_amdgcn_rcpf(1.0f + exp2f(-(k2.x + pa.x)));
                cy += pb.y * __builtin_amdgcn_rcpf(1.0f + exp2f(-(k2.y + pb.x)));
            } else {
                ax += pa.y * __builtin_amdgcn_rcpf(1.0f + exp2f(-(k2.x + pa.x)));
                ay += pb.y * __builtin_amdgcn_rcpf(1.0f + exp2f(-(k2.y + pb.x)));
            }
        }
    }
    for (; i + 4 <= dg; i += 4) {
        int s0 = sp[i], s1 = sp[i + 1], s2 = sp[i + 2], s3 = sp[i + 3];
        uint2 w0 = qvu[(size_t)s0 * 64 + lane];
        uint2 w1 = qvu[(size_t)s1 * 64 + lane];
        uint2 w2 = qvu[(size_t)s2 * 64 + lane];
        uint2 w3 = qvu[(size_t)s3 * 64 + lane];
        float2 p0 = bs2f(w0.x), p1 = bs2f(w0.y);
        float2 p2 = bs2f(w1.x), p3 = bs2f(w1.y);
        float2 p4 = bs2f(w2.x), p5 = bs2f(w2.y);
        float2 p6 = bs2f(w3.x), p7 = bs2f(w3.y);
        ax += p0.y * __builtin_amdgcn_rcpf(1.0f + exp2f(-(k2.x + p0.x)));
        ay += p1.y * __builtin_amdgcn_rcpf(1.0f + exp2f(-(k2.y + p1.x)));
        cx += p2.y * __builtin_amdgcn_rcpf(1.0f + exp2f(-(k2.x + p2.x)));
        cy += p3.y * __builtin_amdgcn_rcpf(1.0f + exp2f(-(k2.y + p3.x)));
        ax += p4.y * __builtin_amdgcn_rcpf(1.0f + exp2f(-(k2.x + p4.x)));
        ay += p5.y * __builtin_amdgcn_rcpf(1.0f + exp2f(-(k2.y + p5.x)));
        cx += p6.y * __builtin_amdgcn_rcpf(1.0f + exp2f(-(k2.x + p6.x)));
        cy += p7.y * __builtin_amdgcn_rcpf(1.0f + exp2f(-(k2.y + p7.x)));
    }
    for (; i < dg; ++i) {
        int s0 = sp[i];
        uint2 w0 = qvu[(size_t)s0 * 64 + lane];
        float2 p0 = bs2f(w0.x), p1 = bs2f(w0.y);
        ax += p0.y * __builtin_amdgcn_rcpf(1.0f + exp2f(-(k2.x + p0.x)));
        ay += p1.y * __builtin_amdgcn_rcpf(1.0f + exp2f(-(k2.y + p1.x)));
    }
    ax += cx; ay += cy;

    float2 sk = bs2f(skipu[(size_t)d * 64 + lane]);
    float2 hi = bs2f(hin1u[(size_t)d * 64 + lane]);
    float2 gv = *(const float2*)(g + lane * 2);
    float2 bt = *(const float2*)(beta + lane * 2);
    float ox = (hi.x + sk.x + ax) * (gv.x * rs) + bt.x;
    float oy = (hi.y + sk.y + ay) * (gv.y * rs) + bt.y;
    hlocal_u[(size_t)d * 64 + lane] = pk2(ox, oy);
}

// ---------------------------------------------------------------------------
// k5: MFMA flash attention (R16-proven). 512 blocks = (b,h,half), 512 thr
// (8 waves, 32 q-rows each). Chunked dbuf K/V staging; exp2 softmax;
// truncation P-pack.
// ---------------------------------------------------------------------------
__device__ __forceinline__ void lswap(unsigned int& X, unsigned int& Y, bool hi) {
    unsigned int Xs = (unsigned int)__shfl_xor((int)X, 32);
    unsigned int Ys = (unsigned int)__shfl_xor((int)Y, 32);
    unsigned int Xn = hi ? Ys : X;
    unsigned int Yn = hi ? Y  : Xs;
    X = Xn; Y = Yn;
}

__global__ __launch_bounds__(512)
void attn_mfma(const short* __restrict__ qkv, short* __restrict__ ctx)
{
    __shared__ __align__(16) char lds[36864];
    // carve: K buf s at lds + s*10240 (128 keys x 40 shorts);
    //        V^T buf s at lds + 20480 + s*8192 (32 rows x 256 B, swizzled)

    const int blk  = blockIdx.x;         // B*H*2 = 512
    const int half = blk & 1;
    const int h    = (blk >> 1) & 3;
    const int b    = blk >> 3;
    const int tid  = threadIdx.x;        // 0..511
    const int lane = tid & 63;
    const int wid  = tid >> 6;           // 0..7
    const int lq = lane & 31;
    const int lg = lane >> 5;
    const size_t gbase = (size_t)(b * 512) * 384 + h * 32;

    const int skey  = tid >> 2;          // 0..127
    const int spart = tid & 3;
    const int vp    = tid & 63;
    const int vdq   = tid >> 6;

    bf8    kst;
    short4 v0s, v1s;

    #define STAGE_LOAD(ck)                                                     \
        kst = *(const bf8*)(qkv + gbase +                                      \
                (size_t)((ck) * 128 + skey) * 384 + 128 + spart * 8);          \
        {                                                                      \
            const short* vr = qkv + gbase +                                    \
                (size_t)((ck) * 128 + 2 * vp) * 384 + 256 + vdq * 4;           \
            v0s = *(const short4*)(vr);                                        \
            v1s = *(const short4*)(vr + 384);                                  \
        }

    #define STAGE_WRITE(s)                                                     \
        *(bf8*)((short*)(lds + (s) * 10240) + skey * 40 + spart * 8) = kst;    \
        {                                                                      \
            char* vb = lds + 20480 + (s) * 8192;                               \
            short v0a[4] = {v0s.x, v0s.y, v0s.z, v0s.w};                       \
            short v1a[4] = {v1s.x, v1s.y, v1s.z, v1s.w};                       \
            _Pragma("unroll")                                                  \
            for (int j = 0; j < 4; ++j) {                                      \
                int d = vdq * 4 + j;                                           \
                unsigned int w = (unsigned int)(unsigned short)v0a[j] |        \
                                 ((unsigned int)(unsigned short)v1a[j] << 16); \
                *(unsigned int*)(vb + d * 256 + ((4 * vp) ^ ((d & 7) << 4))) = w; \
            }                                                                  \
        }

    const int qoff = half * 256 + wid * 32;
    bf8 qf[2];
    #pragma unroll
    for (int kh = 0; kh < 2; ++kh)
        qf[kh] = *(const bf8*)(qkv + gbase +
                       (size_t)(qoff + lq) * 384 + kh * 16 + lg * 8);

    const f32x16 Z16 = {0.f,0.f,0.f,0.f,0.f,0.f,0.f,0.f,0.f,0.f,0.f,0.f,0.f,0.f,0.f,0.f};
    f32x16 o = Z16;
    float mreg = -1e30f;
    float lreg = 0.f;
    const bool hiw = (lg != 0);

    STAGE_LOAD(0);
    STAGE_WRITE(0);
    __syncthreads();

    for (int c = 0; c < 4; ++c) {
        if (c < 3) { STAGE_LOAD(c + 1); }
        const short* Kb = (const short*)(lds + (c & 1) * 10240);
        const char*  Vb = lds + 20480 + (c & 1) * 8192;

        #pragma unroll
        for (int ktl = 0; ktl < 4; ++ktl) {
            bf8 ak[2], vt[2];
            #pragma unroll
            for (int kh = 0; kh < 2; ++kh) {
                ak[kh] = *(const bf8*)(Kb + (ktl * 32 + lq) * 40 + kh * 16 + lg * 8);
                int kbyte = (ktl * 32 + kh * 16 + lg * 8) * 2;   // 0..254
                vt[kh] = *(const bf8*)(Vb + lq * 256 + (kbyte ^ ((lq & 7) << 4)));
            }
            f32x16 s = Z16;
            s = __builtin_amdgcn_mfma_f32_32x32x16_bf16(ak[0], qf[0], s, 0, 0, 0);
            s = __builtin_amdgcn_mfma_f32_32x32x16_bf16(ak[1], qf[1], s, 0, 0, 0);
            float t0 = fmaxf(fmaxf(s[0],  s[1]),  s[2]);
            float t1 = fmaxf(fmaxf(s[3],  s[4]),  s[5]);
            float t2 = fmaxf(fmaxf(s[6],  s[7]),  s[8]);
            float t3 = fmaxf(fmaxf(s[9],  s[10]), s[11]);
            float t4 = fmaxf(fmaxf(s[12], s[13]), s[14]);
            float mt = fmaxf(fmaxf(fmaxf(t0, t1), t2), fmaxf(fmaxf(t3, t4), s[15]));
            mt = fmaxf(mt, __shfl_xor(mt, 32));
            if (__any(mt > mreg + 11.5415603f)) {    // defer-max, log2 domain
                float mnew = fmaxf(mreg, mt);
                float corr = exp2f(mreg - mnew);
                mreg = mnew;
                lreg *= corr;
                #pragma unroll
                for (int r = 0; r < 16; ++r) o[r] *= corr;
            }
            float m = mreg;
            float p[16]; float ps = 0.f;
            #pragma unroll
            for (int r = 0; r < 16; ++r) { p[r] = exp2f(s[r] - m); ps += p[r]; }
            ps += __shfl_xor(ps, 32);
            lreg += ps;
            unsigned int w0 = pk2t(p[0],  p[1]),  w1 = pk2t(p[2],  p[3]);
            unsigned int w2 = pk2t(p[4],  p[5]),  w3 = pk2t(p[6],  p[7]);
            unsigned int w4 = pk2t(p[8],  p[9]),  w5 = pk2t(p[10], p[11]);
            unsigned int w6 = pk2t(p[12], p[13]), w7 = pk2t(p[14], p[15]);
            lswap(w0, w2, hiw); lswap(w1, w3, hiw);
            lswap(w4, w6, hiw); lswap(w5, w7, hiw);
            union { unsigned int u[4]; bf8 v; } P0, P1;
            P0.u[0] = w0; P0.u[1] = w1; P0.u[2] = w2; P0.u[3] = w3;
            P1.u[0] = w4; P1.u[1] = w5; P1.u[2] = w6; P1.u[3] = w7;
            o = __builtin_amdgcn_mfma_f32_32x32x16_bf16(vt[0], P0.v, o, 0, 0, 0);
            o = __builtin_amdgcn_mfma_f32_32x32x16_bf16(vt[1], P1.v, o, 0, 0, 0);
        }
        if (c < 3) { STAGE_WRITE((c + 1) & 1); }
        __syncthreads();
    }
    #undef STAGE_LOAD
    #undef STAGE_WRITE

    // epilogue: O^T regs -> LDS (swizzled, 16 KB) -> coalesced global
    {
        float inv = 1.0f / lreg;
        int ql = wid * 32 + lq;            // 0..255 (block-local q)
        #pragma unroll
        for (int b4 = 0; b4 < 4; ++b4) {
            short4 pkv;
            pkv.x = f2bs(o[b4 * 4 + 0] * inv);
            pkv.y = f2bs(o[b4 * 4 + 1] * inv);
            pkv.z = f2bs(o[b4 * 4 + 2] * inv);
            pkv.w = f2bs(o[b4 * 4 + 3] * inv);
            int dbyte = (8 * b4 + 4 * lg) * 2;
            *(short4*)(lds + ql * 64 + (dbyte ^ ((ql & 7) << 3))) = pkv;
        }
    }
    __syncthreads();
    {
        int row  = tid >> 1;                // 0..255
        int pbase = (tid & 1) * 4;          // 0 or 4
        short* dst = ctx + (size_t)(b * 512 + half * 256 + row) * 128 + h * 32;
        #pragma unroll
        for (int i = 0; i < 4; ++i) {
            int part = pbase + i;           // 0..7
            short4 pv = *(short4*)(lds + row * 64 + ((part * 8) ^ ((row & 7) << 3)));
            *(short4*)(dst + part * 4) = pv;
        }
    }
}

// ---------------------------------------------------------------------------
// k6: FUSED out_proj+combine+FFN+finalBN (R11-proven). 512 blocks.
// ---------------------------------------------------------------------------
__global__ __launch_bounds__(256)
void outproj_ff_kernel(const short* __restrict__ ctxb, const short* __restrict__ wbf,
                       const float* __restrict__ bout,
                       const short* __restrict__ hin1b, const short* __restrict__ hlocb,
                       const float* __restrict__ g1a, const float* __restrict__ b1a,
                       const float* __restrict__ b1, const float* __restrict__ b2,
                       const float* __restrict__ g2, const float* __restrict__ b2g,
                       float* __restrict__ out)
{
    __shared__ __align__(16) short ldsH[64 * 128];   // 16 KB, byte ^ ((row&7)<<4)
    __shared__ __align__(16) short ldsF[64 * 256];   // 32 KB, byte ^ ((row&7)<<4)
    const int my = blockIdx.x;
    const int lane = threadIdx.x & 63;
    const int wid  = threadIdx.x >> 6;
    const int lrow = lane & 15;
    const int lk   = (lane >> 4) * 8;
    const int rbase = (lane >> 4) * 4;
    const float rs = 0.9999950000374998f;

    // ---- phase 0: out_proj + combine -> ldsH ----
    {
        const int m0 = (wid >> 1) * 32;
        const int n0 = (wid & 1) * 64;
        f32x4 acc[2][4] = {};
        const short* Ap = ctxb + (size_t)(my * 64 + m0 + lrow) * 128 + lk;
        const short* Wp = wbf + 131072 + (size_t)(n0 + lrow) * 128 + lk;
        #pragma unroll
        for (int ks = 0; ks < 128; ks += 32) {
            bf8 af[2], wf[4];
            af[0] = *(const bf8*)(Ap + ks);
            af[1] = *(const bf8*)(Ap + 16 * 128 + ks);
            #pragma unroll
            for (int j = 0; j < 4; ++j) wf[j] = *(const bf8*)(Wp + (size_t)j * 16 * 128 + ks);
            #pragma unroll
            for (int i = 0; i < 2; ++i)
                #pragma unroll
                for (int j = 0; j < 4; ++j)
                    acc[i][j] = __builtin_amdgcn_mfma_f32_16x16x32_bf16(af[i], wf[j], acc[i][j], 0, 0, 0);
        }
        #pragma unroll
        for (int j = 0; j < 4; ++j) {
            int col = n0 + j * 16 + lrow;            // 0..127
            float bcol = bout[col];
            float gsc = g1a[col] * rs;
            float bsc = b1a[col];
            #pragma unroll
            for (int i = 0; i < 2; ++i)
                #pragma unroll
                for (int r = 0; r < 4; ++r) {
                    int rl = m0 + i * 16 + rbase + r;
                    size_t idx = (size_t)(my * 64 + rl) * 128 + col;
                    float v = acc[i][j][r] + bcol;
                    float o = bs1f(hlocb[idx]) + (bs1f(hin1b[idx]) + v) * gsc + bsc;
                    int byte = (rl * 256 + col * 2) ^ ((rl & 7) << 4);
                    *(short*)((char*)ldsH + byte) = f2bs(o);
                }
        }
    }
    __syncthreads();
    // ---- phase 1: ff1 -> ldsF ----
    {
        const int m0 = (wid >> 1) * 32;
        const int n0 = (wid & 1) * 128;
        f32x4 acc[2][8] = {};
        const short* Wp = wbf + 147456 + (size_t)(n0 + lrow) * 128 + lk;
        #pragma unroll
        for (int ks = 0; ks < 128; ks += 32) {
            bf8 af[2], wf[8];
            #pragma unroll
            for (int i = 0; i < 2; ++i) {
                int row = m0 + lrow + i * 16;
                int byte = (row * 256 + (ks + lk) * 2) ^ ((row & 7) << 4);
                af[i] = *(const bf8*)((const char*)ldsH + byte);
            }
            #pragma unroll
            for (int j = 0; j < 8; ++j) wf[j] = *(const bf8*)(Wp + (size_t)j * 16 * 128 + ks);
            #pragma unroll
            for (int i = 0; i < 2; ++i)
                #pragma unroll
                for (int j = 0; j < 8; ++j)
                    acc[i][j] = __builtin_amdgcn_mfma_f32_16x16x32_bf16(af[i], wf[j], acc[i][j], 0, 0, 0);
        }
        #pragma unroll
        for (int j = 0; j < 8; ++j) {
            int col = n0 + j * 16 + lrow;            // 0..255
            float bc = b1[col];
            #pragma unroll
            for (int i = 0; i < 2; ++i)
                #pragma unroll
                for (int r = 0; r < 4; ++r) {
                    int rl = m0 + i * 16 + rbase + r;
                    float v = fmaxf(acc[i][j][r] + bc, 0.f);
                    int byte = (rl * 512 + col * 2) ^ ((rl & 7) << 4);
                    *(short*)((char*)ldsF + byte) = f2bs(v);
                }
        }
    }
    __syncthreads();
    // ---- phase 2: ff2 + final BN (residual from ldsH) ----
    {
        const int m0 = (wid >> 1) * 32;
        const int n0 = (wid & 1) * 64;
        f32x4 acc[2][4] = {};
        const short* Wp = wbf + 180224 + (size_t)(n0 + lrow) * 256 + lk;
        #pragma unroll
        for (int ks = 0; ks < 256; ks += 32) {
            bf8 af[2], wf[4];
            #pragma unroll
            for (int i = 0; i < 2; ++i) {
                int row = m0 + lrow + i * 16;
                int byte = (row * 512 + (ks + lk) * 2) ^ ((row & 7) << 4);
                af[i] = *(const bf8*)((const char*)ldsF + byte);
            }
            #pragma unroll
            for (int j = 0; j < 4; ++j) wf[j] = *(const bf8*)(Wp + (size_t)j * 16 * 256 + ks);
            #pragma unroll
            for (int i = 0; i < 2; ++i)
                #pragma unroll
                for (int j = 0; j < 4; ++j)
                    acc[i][j] = __builtin_amdgcn_mfma_f32_16x16x32_bf16(af[i], wf[j], acc[i][j], 0, 0, 0);
        }
        #pragma unroll
        for (int j = 0; j < 4; ++j) {
            int col = n0 + j * 16 + lrow;
            float bc = b2[col];
            float gsc = g2[col] * rs;
            float bsc = b2g[col];
            #pragma unroll
            for (int i = 0; i < 2; ++i)
                #pragma unroll
                for (int r = 0; r < 4; ++r) {
                    int rl = m0 + i * 16 + rbase + r;
                    int hbyte = (rl * 256 + col * 2) ^ ((rl & 7) << 4);
                    float hres = bs1f(*(const short*)((const char*)ldsH + hbyte));
                    float v = acc[i][j][r] + bc;
                    out[(size_t)(my * 64 + rl) * 128 + col] = (hres + v) * gsc + bsc;
                }
        }
    }
}

// ---------------------------------------------------------------------------
extern "C" void kernel_launch(void* const* d_in, const int* in_sizes, int n_in,
                              void* d_out, int out_size, void* d_ws, size_t ws_size,
                              hipStream_t stream)
{
    (void)in_sizes; (void)n_in; (void)out_size; (void)ws_size;

    const float* x    = (const float*)d_in[0];
    const int*   ei   = (const int*)d_in[1];
    const float* Wres = (const float*)d_in[3];
    const float* bres = (const float*)d_in[4];
    const float* Wk   = (const float*)d_in[5];
    const float* bk   = (const float*)d_in[6];
    const float* Wq   = (const float*)d_in[7];
    const float* bq   = (const float*)d_in[8];
    const float* Wv   = (const float*)d_in[9];
    const float* bv   = (const float*)d_in[10];
    const float* Wsk  = (const float*)d_in[11];
    const float* bsk  = (const float*)d_in[12];
    const float* g1l  = (const float*)d_in[13];
    const float* b1l  = (const float*)d_in[14];
    const float* g1a  = (const float*)d_in[15];
    const float* b1a  = (const float*)d_in[16];
    const float* Win  = (const float*)d_in[17];
    const float* bin  = (const float*)d_in[18];
    const float* Wout = (const float*)d_in[19];
    const float* bout = (const float*)d_in[20];
    const float* W1   = (const float*)d_in[21];
    const float* b1   = (const float*)d_in[22];
    const float* W2   = (const float*)d_in[23];
    const float* b2   = (const float*)d_in[24];
    const float* g2   = (const float*)d_in[25];
    const float* b2g  = (const float*)d_in[26];
    float* out = (float*)d_out;

    float* ws = (float*)d_ws;
    // ----- workspace layout (float-slot offsets), lifetimes k0..k6 -----
    short* hin1b = (short*)ws;                        // [0,0.5NM)  w:k2 r:k3,k4,k6
    short* kbv   = (short*)(ws + NM / 2);             // [0.5NM,NM) w:k2 r:k4
    short* qvb   = (short*)(ws + NM);                 // [NM,2NM)   w:k2 r:k4 (q,v ilv)
    short* skipb = (short*)(ws + 2 * NM);             // [2NM,2.5NM) w:k2 r:k4
    short* xb    = (short*)(ws + 2 * NM + NM / 2);    // [2.5NM,3NM) w:k1 r:k2
    short* qkvb  = (short*)(ws + 3 * NM);             // [3NM,4.5NM) w:k3 r:k5
    short* hlocb = (short*)(ws + 4 * NM + NM / 2);    // [4.5NM,5NM) w:k4 r:k6
    // slot ints/ushorts overlay [5NM, ...) — dead after k4; ctxb (w:k5) reuses it
    int* deg = (int*)(ws + 5 * NM);                   // [N] w:k0, rmw:k1 r:k4
    unsigned short* slots = (unsigned short*)(deg + N_NODES);  // [N*CAP] w:k1 r:k4
    short* ctxb  = (short*)(ws + 5 * NM);             // [5NM,5.5NM) w:k5 r:k6
    short* wbf   = (short*)(ws + 6 * NM);             // 212992 shorts = 106496 fslots
    float* bcat  = ws + 6 * NM + 106496;              // [640] f32
    // total extent: 6NM + 107136 floats ≈ 101.1 MB

    dim3 blk(256);
    // 1/sqrt(32) * log2(e)  (exp2-domain softmax)
    const float qscale = 0.17677669529663687f * 1.4426950408889634f;

    // 0. zero deg
    zero_deg_kernel<<<dim3(32), blk, 0, stream>>>((int4*)deg);

    // 1. scatter (first) + cvt
    cvt_scatter_kernel<<<dim3(6353), blk, 0, stream>>>(
        x, Wres, Wk, Wq, Wv, Wsk, Win, Wout, W1, W2,
        bres, bk, bq, bv, bsk, ei, xb, wbf, bcat, deg, slots);

    // 2. proj5 GEMM (merged 5 groups; k,q pre-scaled by log2e)
    proj5_kernel<<<dim3(512), blk, 0, stream>>>(
        xb, wbf, bcat, hin1b, kbv, (unsigned int*)qvb, skipb);

    // 3. in_proj GEMM (merged 3 groups)
    inproj_kernel<<<dim3(512), blk, 0, stream>>>(
        hin1b, wbf, bin, qkvb, qscale);

    // 4. gather + skip + BN (slot lists; exp2 sigmoid; vector slot loads)
    gather_local_kernel<<<dim3(N_NODES / 4), blk, 0, stream>>>(
        (const unsigned int*)kbv, (const uint2*)qvb, (const unsigned int*)skipb,
        (const unsigned int*)hin1b, deg, slots, g1l, b1l,
        (unsigned int*)hlocb);

    // 5. attention (512 blocks x 512 thr, 2 blocks/CU; trunc P-pack)
    attn_mfma<<<dim3(512), dim3(512), 0, stream>>>(qkvb, ctxb);

    // 6. fused out_proj + combine + FFN + final BN
    outproj_ff_kernel<<<dim3(512), blk, 0, stream>>>(
        ctxb, wbf, bout, hin1b, hlocb, g1a, b1a, b1, b2, g2, b2g, out);
}

// Round 23
// 182.482 us; speedup vs baseline: 1.0080x; 1.0061x over previous
//
#include <hip/hip_runtime.h>
#include <math.h>

#define N_NODES 32768
#define N_EDGES 524288
#define DIM     128
#define CAP     80

static constexpr size_t NM = (size_t)N_NODES * DIM;   // 4194304

typedef __attribute__((ext_vector_type(8)))  short bf8;     // 8 bf16
typedef __attribute__((ext_vector_type(4)))  float f32x4;
typedef __attribute__((ext_vector_type(16))) float f32x16;

__device__ __forceinline__ short f2bs(float x) {
    union { float f; unsigned int u; } v; v.f = x;
    unsigned int r = v.u + 0x7fffu + ((v.u >> 16) & 1u);
    return (short)(r >> 16);
}
__device__ __forceinline__ unsigned int pk2(float a, float b) {
    return (unsigned int)(unsigned short)f2bs(a) |
           ((unsigned int)(unsigned short)f2bs(b) << 16);
}
// truncation pack (P in (0,1]: rel err <= 2^-8, cheap: 3 ops)
__device__ __forceinline__ unsigned int pk2t(float a, float b) {
    union { float f; unsigned int u; } ua, ub; ua.f = a; ub.f = b;
    return (ua.u >> 16) | (ub.u & 0xffff0000u);
}
__device__ __forceinline__ float2 bs2f(unsigned int u) {
    union { unsigned int a; float f; } lo, hi;
    lo.a = u << 16; hi.a = u & 0xffff0000u;
    float2 r; r.x = lo.f; r.y = hi.f; return r;
}
__device__ __forceinline__ float bs1f(short s) {
    union { unsigned int a; float f; } t;
    t.a = ((unsigned int)(unsigned short)s) << 16; return t.f;
}

// ---------------------------------------------------------------------------
// k0: zero deg.
// ---------------------------------------------------------------------------
__global__ __launch_bounds__(256)
void zero_deg_kernel(int4* __restrict__ deg4)
{
    deg4[blockIdx.x * 256 + threadIdx.x] = make_int4(0, 0, 0, 0);  // 8192 int4
}

// ---------------------------------------------------------------------------
// k1: scatter + cvt (R13-proven). blocks [0,2048): slot scatter first;
// [2048,6353): x->bf16, weights->wbf, biases->bcat.
// ---------------------------------------------------------------------------
__global__ __launch_bounds__(256)
void cvt_scatter_kernel(const float* __restrict__ x,
                        const float* __restrict__ w0, const float* __restrict__ w1,
                        const float* __restrict__ w2, const float* __restrict__ w3,
                        const float* __restrict__ w4, const float* __restrict__ w5,
                        const float* __restrict__ w6, const float* __restrict__ w7,
                        const float* __restrict__ w8,
                        const float* __restrict__ b0, const float* __restrict__ b1,
                        const float* __restrict__ b2, const float* __restrict__ b3,
                        const float* __restrict__ b4,
                        const int* __restrict__ ei,
                        short* __restrict__ xb, short* __restrict__ wbf,
                        float* __restrict__ bcat,
                        int* __restrict__ deg, unsigned short* __restrict__ slots)
{
    if (blockIdx.x < 2048) {
        int e = blockIdx.x * 256 + threadIdx.x;            // 0..524287
        int d = ei[N_EDGES + e];
        int pos = atomicAdd(&deg[d], 1);
        if (pos < CAP) slots[d * CAP + pos] = (unsigned short)ei[e];
        return;
    }
    long long t = (long long)(blockIdx.x - 2048) * 256 + threadIdx.x;
    long long i4 = t * 4;
    if (i4 < (long long)NM) {
        float4 v = *(const float4*)(x + i4);
        short4 o; o.x = f2bs(v.x); o.y = f2bs(v.y); o.z = f2bs(v.z); o.w = f2bs(v.w);
        *(short4*)(xb + i4) = o;
    } else {
        int j = (int)(i4 - (long long)NM);
        if (j < 212992) {
            const float* src; int off;
            if      (j <  16384) { src = w0; off = 0; }
            else if (j <  32768) { src = w1; off = 16384; }
            else if (j <  49152) { src = w2; off = 32768; }
            else if (j <  65536) { src = w3; off = 49152; }
            else if (j <  81920) { src = w4; off = 65536; }
            else if (j < 131072) { src = w5; off = 81920; }
            else if (j < 147456) { src = w6; off = 131072; }
            else if (j < 180224) { src = w7; off = 147456; }
            else                 { src = w8; off = 180224; }
            float4 v = *(const float4*)(src + (j - off));
            short4 o; o.x = f2bs(v.x); o.y = f2bs(v.y); o.z = f2bs(v.z); o.w = f2bs(v.w);
            *(short4*)(wbf + j) = o;
        } else if (j < 213632) {
            int jb = j - 212992;                 // 0..639
            int grp = jb >> 7, loc = jb & 127;
            const float* bs = (grp == 0) ? b0 : (grp == 1) ? b1 :
                              (grp == 2) ? b2 : (grp == 3) ? b3 : b4;
            float4 v = *(const float4*)(bs + loc);
            *(float4*)(bcat + jb) = v;
        }
    }
}

// ---------------------------------------------------------------------------
// k2: proj5 MERGED (R16-proven). One block (64 rows), all 5 projections.
// ---------------------------------------------------------------------------
__global__ __launch_bounds__(256)
void proj5_kernel(const short* __restrict__ xb, const short* __restrict__ wbf,
                  const float* __restrict__ bcat,
                  short* __restrict__ hin1b, short* __restrict__ kbv,
                  unsigned int* __restrict__ qvu, short* __restrict__ skipb)
{
    const int my = blockIdx.x;            // 0..511
    const int lane = threadIdx.x & 63;
    const int wid  = threadIdx.x >> 6;
    const int m0 = my * 64 + (wid >> 1) * 32;
    const int n0 = (wid & 1) * 64;
    const int lrow = lane & 15;
    const int lk   = (lane >> 4) * 8;

    bf8 af[2][4];
    const short* Ap = xb + (size_t)(m0 + lrow) * 128 + lk;
    #pragma unroll
    for (int i = 0; i < 2; ++i)
        #pragma unroll
        for (int ks = 0; ks < 4; ++ks)
            af[i][ks] = *(const bf8*)(Ap + (size_t)i * 16 * 128 + ks * 32);

    f32x4 acc[5][2][4] = {};
    #pragma unroll
    for (int ks = 0; ks < 4; ++ks) {
        #pragma unroll
        for (int g = 0; g < 5; ++g) {
            bf8 wf[4];
            const short* Wp = wbf + g * 16384 + (size_t)(n0 + lrow) * 128 + ks * 32 + lk;
            #pragma unroll
            for (int j = 0; j < 4; ++j)
                wf[j] = *(const bf8*)(Wp + (size_t)j * 16 * 128);
            #pragma unroll
            for (int i = 0; i < 2; ++i)
                #pragma unroll
                for (int j = 0; j < 4; ++j)
                    acc[g][i][j] = __builtin_amdgcn_mfma_f32_16x16x32_bf16(
                                       af[i][ks], wf[j], acc[g][i][j], 0, 0, 0);
        }
    }

    const int rbase = (lane >> 4) * 4;
    #pragma unroll
    for (int j = 0; j < 4; ++j) {
        int col = n0 + j * 16 + lrow;                 // 0..127
        float b0c = bcat[col],       b1c = bcat[128 + col];
        float b2c = bcat[256 + col], b3c = bcat[384 + col];
        float b4c = bcat[512 + col];
        #pragma unroll
        for (int i = 0; i < 2; ++i)
            #pragma unroll
            for (int r = 0; r < 4; ++r) {
                int row = m0 + i * 16 + rbase + r;
                size_t ridx = (size_t)row * 128 + col;
                hin1b[ridx] = f2bs(fmaxf(acc[0][i][j][r] + b0c, 0.f));
                kbv[ridx]   = f2bs(acc[1][i][j][r] + b1c);
                qvu[ridx]   = pk2(acc[2][i][j][r] + b2c, acc[3][i][j][r] + b3c);
                skipb[ridx] = f2bs(acc[4][i][j][r] + b4c);
            }
    }
}

// ---------------------------------------------------------------------------
// k3: in_proj MERGED — one block (64 rows) computes all 3 output groups
// (q|k|v cols 0..383). A loaded once; acc[3][2][4]; q pre-scaled. 512 blocks.
// ---------------------------------------------------------------------------
__global__ __launch_bounds__(256)
void inproj_kernel(const short* __restrict__ hin1b, const short* __restrict__ wbf,
                   const float* __restrict__ bin, short* __restrict__ qkvb,
                   float qscale)
{
    const int my = blockIdx.x;            // 0..511
    const int lane = threadIdx.x & 63;
    const int wid  = threadIdx.x >> 6;
    const int m0 = my * 64 + (wid >> 1) * 32;
    const int n0 = (wid & 1) * 64;
    const int lrow = lane & 15;
    const int lk   = (lane >> 4) * 8;

    bf8 af[2][4];
    const short* Ap = hin1b + (size_t)(m0 + lrow) * 128 + lk;
    #pragma unroll
    for (int i = 0; i < 2; ++i)
        #pragma unroll
        for (int ks = 0; ks < 4; ++ks)
            af[i][ks] = *(const bf8*)(Ap + (size_t)i * 16 * 128 + ks * 32);

    f32x4 acc[3][2][4] = {};
    #pragma unroll
    for (int ks = 0; ks < 4; ++ks) {
        #pragma unroll
        for (int g = 0; g < 3; ++g) {
            bf8 wf[4];
            const short* Wp = wbf + 81920 + (size_t)(g * 128 + n0 + lrow) * 128
                              + ks * 32 + lk;
            #pragma unroll
            for (int j = 0; j < 4; ++j)
                wf[j] = *(const bf8*)(Wp + (size_t)j * 16 * 128);
            #pragma unroll
            for (int i = 0; i < 2; ++i)
                #pragma unroll
                for (int j = 0; j < 4; ++j)
                    acc[g][i][j] = __builtin_amdgcn_mfma_f32_16x16x32_bf16(
                                       af[i][ks], wf[j], acc[g][i][j], 0, 0, 0);
        }
    }

    const int rbase = (lane >> 4) * 4;
    #pragma unroll
    for (int g = 0; g < 3; ++g) {
        float sc = (g == 0) ? qscale : 1.0f;
        #pragma unroll
        for (int j = 0; j < 4; ++j) {
            int col = g * 128 + n0 + j * 16 + lrow;   // 0..383
            float bcol = bin[col];
            #pragma unroll
            for (int i = 0; i < 2; ++i)
                #pragma unroll
                for (int r = 0; r < 4; ++r) {
                    int row = m0 + i * 16 + rbase + r;
                    float v = (acc[g][i][j][r] + bcol) * sc;
                    qkvb[(size_t)row * 384 + col] = f2bs(v);
                }
        }
    }
}

// ---------------------------------------------------------------------------
// k4: gather via slot lists (R16-proven). One wave/node, 8-edge unroll.
// ---------------------------------------------------------------------------
__global__ __launch_bounds__(256)
void gather_local_kernel(const unsigned int* __restrict__ kbu,
                         const uint2* __restrict__ qvu,
                         const unsigned int* __restrict__ skipu,
                         const unsigned int* __restrict__ hin1u,
                         const int* __restrict__ deg,
                         const unsigned short* __restrict__ slots,
                         const float* __restrict__ g, const float* __restrict__ beta,
                         unsigned int* __restrict__ hlocal_u)
{
    const int d    = blockIdx.x * 4 + (threadIdx.x >> 6);
    const int lane = threadIdx.x & 63;          // owns cols 2l, 2l+1
    const float rs = 0.9999950000374998f;       // 1/sqrt(1+1e-5)

    float2 k2 = bs2f(kbu[(size_t)d * 64 + lane]);
    int dg = deg[d]; if (dg > CAP) dg = CAP;
    const unsigned short* sp = slots + (size_t)d * CAP;
    int i = 0;

    float ax = 0.f, ay = 0.f, cx = 0.f, cy = 0.f;
    for (; i + 8 <= dg; i += 8) {
        int s[8];
        #pragma unroll
        for (int u = 0; u < 8; ++u) s[u] = sp[i + u];
        uint2 w[8];
        #pragma unroll
        for (int u = 0; u < 8; ++u) w[u] = qvu[(size_t)s[u] * 64 + lane];
        #pragma unroll
        for (int u = 0; u < 8; ++u) {
            float2 pa = bs2f(w[u].x), pb = bs2f(w[u].y);
            if (u & 1) {
                cx += pa.y * __builtin_amdgcn_rcpf(1.0f + __expf(-(k2.x + pa.x)));
                cy += pb.y * __builtin_amdgcn_rcpf(1.0f + __expf(-(k2.y + pb.x)));
            } else {
                ax += pa.y * __builtin_amdgcn_rcpf(1.0f + __expf(-(k2.x + pa.x)));
                ay += pb.y * __builtin_amdgcn_rcpf(1.0f + __expf(-(k2.y + pb.x)));
            }
        }
    }
    for (; i + 4 <= dg; i += 4) {
        int s0 = sp[i], s1 = sp[i + 1], s2 = sp[i + 2], s3 = sp[i + 3];
        uint2 w0 = qvu[(size_t)s0 * 64 + lane];
        uint2 w1 = qvu[(size_t)s1 * 64 + lane];
        uint2 w2 = qvu[(size_t)s2 * 64 + lane];
        uint2 w3 = qvu[(size_t)s3 * 64 + lane];
        float2 p0 = bs2f(w0.x), p1 = bs2f(w0.y);
        float2 p2 = bs2f(w1.x), p3 = bs2f(w1.y);
        float2 p4 = bs2f(w2.x), p5 = bs2f(w2.y);
        float2 p6 = bs2f(w3.x), p7 = bs2f(w3.y);
        ax += p0.y * __builtin_amdgcn_rcpf(1.0f + __expf(-(k2.x + p0.x)));
        ay += p1.y * __builtin_amdgcn_rcpf(1.0f + __expf(-(k2.y + p1.x)));
        cx += p2.y * __builtin_amdgcn_rcpf(1.0f + __expf(-(k2.x + p2.x)));
        cy += p3.y * __builtin_amdgcn_rcpf(1.0f + __expf(-(k2.y + p3.x)));
        ax += p4.y * __builtin_amdgcn_rcpf(1.0f + __expf(-(k2.x + p4.x)));
        ay += p5.y * __builtin_amdgcn_rcpf(1.0f + __expf(-(k2.y + p5.x)));
        cx += p6.y * __builtin_amdgcn_rcpf(1.0f + __expf(-(k2.x + p6.x)));
        cy += p7.y * __builtin_amdgcn_rcpf(1.0f + __expf(-(k2.y + p7.x)));
    }
    for (; i < dg; ++i) {
        int s0 = sp[i];
        uint2 w0 = qvu[(size_t)s0 * 64 + lane];
        float2 p0 = bs2f(w0.x), p1 = bs2f(w0.y);
        ax += p0.y * __builtin_amdgcn_rcpf(1.0f + __expf(-(k2.x + p0.x)));
        ay += p1.y * __builtin_amdgcn_rcpf(1.0f + __expf(-(k2.y + p1.x)));
    }
    ax += cx; ay += cy;

    float2 sk = bs2f(skipu[(size_t)d * 64 + lane]);
    float2 hi = bs2f(hin1u[(size_t)d * 64 + lane]);
    float2 gv = *(const float2*)(g + lane * 2);
    float2 bt = *(const float2*)(beta + lane * 2);
    float ox = (hi.x + sk.x + ax) * (gv.x * rs) + bt.x;
    float oy = (hi.y + sk.y + ay) * (gv.y * rs) + bt.y;
    hlocal_u[(size_t)d * 64 + lane] = pk2(ox, oy);
}

// ---------------------------------------------------------------------------
// k5: MFMA flash attention (R16-proven). 512 blocks = (b,h,half), 512 thr
// (8 waves, 32 q-rows each). Chunked dbuf K/V staging; exp2 softmax;
// truncation P-pack.
// ---------------------------------------------------------------------------
__device__ __forceinline__ void lswap(unsigned int& X, unsigned int& Y, bool hi) {
    unsigned int Xs = (unsigned int)__shfl_xor((int)X, 32);
    unsigned int Ys = (unsigned int)__shfl_xor((int)Y, 32);
    unsigned int Xn = hi ? Ys : X;
    unsigned int Yn = hi ? Y  : Xs;
    X = Xn; Y = Yn;
}

__global__ __launch_bounds__(512)
void attn_mfma(const short* __restrict__ qkv, short* __restrict__ ctx)
{
    __shared__ __align__(16) char lds[36864];
    // carve: K buf s at lds + s*10240 (128 keys x 40 shorts);
    //        V^T buf s at lds + 20480 + s*8192 (32 rows x 256 B, swizzled)

    const int blk  = blockIdx.x;         // B*H*2 = 512
    const int half = blk & 1;
    const int h    = (blk >> 1) & 3;
    const int b    = blk >> 3;
    const int tid  = threadIdx.x;        // 0..511
    const int lane = tid & 63;
    const int wid  = tid >> 6;           // 0..7
    const int lq = lane & 31;
    const int lg = lane >> 5;
    const size_t gbase = (size_t)(b * 512) * 384 + h * 32;

    const int skey  = tid >> 2;          // 0..127
    const int spart = tid & 3;
    const int vp    = tid & 63;
    const int vdq   = tid >> 6;

    bf8    kst;
    short4 v0s, v1s;

    #define STAGE_LOAD(ck)                                                     \
        kst = *(const bf8*)(qkv + gbase +                                      \
                (size_t)((ck) * 128 + skey) * 384 + 128 + spart * 8);          \
        {                                                                      \
            const short* vr = qkv + gbase +                                    \
                (size_t)((ck) * 128 + 2 * vp) * 384 + 256 + vdq * 4;           \
            v0s = *(const short4*)(vr);                                        \
            v1s = *(const short4*)(vr + 384);                                  \
        }

    #define STAGE_WRITE(s)                                                     \
        *(bf8*)((short*)(lds + (s) * 10240) + skey * 40 + spart * 8) = kst;    \
        {                                                                      \
            char* vb = lds + 20480 + (s) * 8192;                               \
            short v0a[4] = {v0s.x, v0s.y, v0s.z, v0s.w};                       \
            short v1a[4] = {v1s.x, v1s.y, v1s.z, v1s.w};                       \
            _Pragma("unroll")                                                  \
            for (int j = 0; j < 4; ++j) {                                      \
                int d = vdq * 4 + j;                                           \
                unsigned int w = (unsigned int)(unsigned short)v0a[j] |        \
                                 ((unsigned int)(unsigned short)v1a[j] << 16); \
                *(unsigned int*)(vb + d * 256 + ((4 * vp) ^ ((d & 7) << 4))) = w; \
            }                                                                  \
        }

    const int qoff = half * 256 + wid * 32;
    bf8 qf[2];
    #pragma unroll
    for (int kh = 0; kh < 2; ++kh)
        qf[kh] = *(const bf8*)(qkv + gbase +
                       (size_t)(qoff + lq) * 384 + kh * 16 + lg * 8);

    const f32x16 Z16 = {0.f,0.f,0.f,0.f,0.f,0.f,0.f,0.f,0.f,0.f,0.f,0.f,0.f,0.f,0.f,0.f};
    f32x16 o = Z16;
    float mreg = -1e30f;
    float lreg = 0.f;
    const bool hiw = (lg != 0);

    STAGE_LOAD(0);
    STAGE_WRITE(0);
    __syncthreads();

    for (int c = 0; c < 4; ++c) {
        if (c < 3) { STAGE_LOAD(c + 1); }
        const short* Kb = (const short*)(lds + (c & 1) * 10240);
        const char*  Vb = lds + 20480 + (c & 1) * 8192;

        #pragma unroll
        for (int ktl = 0; ktl < 4; ++ktl) {
            bf8 ak[2], vt[2];
            #pragma unroll
            for (int kh = 0; kh < 2; ++kh) {
                ak[kh] = *(const bf8*)(Kb + (ktl * 32 + lq) * 40 + kh * 16 + lg * 8);
                int kbyte = (ktl * 32 + kh * 16 + lg * 8) * 2;   // 0..254
                vt[kh] = *(const bf8*)(Vb + lq * 256 + (kbyte ^ ((lq & 7) << 4)));
            }
            f32x16 s = Z16;
            s = __builtin_amdgcn_mfma_f32_32x32x16_bf16(ak[0], qf[0], s, 0, 0, 0);
            s = __builtin_amdgcn_mfma_f32_32x32x16_bf16(ak[1], qf[1], s, 0, 0, 0);
            float t0 = fmaxf(fmaxf(s[0],  s[1]),  s[2]);
            float t1 = fmaxf(fmaxf(s[3],  s[4]),  s[5]);
            float t2 = fmaxf(fmaxf(s[6],  s[7]),  s[8]);
            float t3 = fmaxf(fmaxf(s[9],  s[10]), s[11]);
            float t4 = fmaxf(fmaxf(s[12], s[13]), s[14]);
            float mt = fmaxf(fmaxf(fmaxf(t0, t1), t2), fmaxf(fmaxf(t3, t4), s[15]));
            mt = fmaxf(mt, __shfl_xor(mt, 32));
            if (__any(mt > mreg + 11.5415603f)) {    // defer-max, log2 domain
                float mnew = fmaxf(mreg, mt);
                float corr = exp2f(mreg - mnew);
                mreg = mnew;
                lreg *= corr;
                #pragma unroll
                for (int r = 0; r < 16; ++r) o[r] *= corr;
            }
            float m = mreg;
            float p[16]; float ps = 0.f;
            #pragma unroll
            for (int r = 0; r < 16; ++r) { p[r] = exp2f(s[r] - m); ps += p[r]; }
            ps += __shfl_xor(ps, 32);
            lreg += ps;
            unsigned int w0 = pk2t(p[0],  p[1]),  w1 = pk2t(p[2],  p[3]);
            unsigned int w2 = pk2t(p[4],  p[5]),  w3 = pk2t(p[6],  p[7]);
            unsigned int w4 = pk2t(p[8],  p[9]),  w5 = pk2t(p[10], p[11]);
            unsigned int w6 = pk2t(p[12], p[13]), w7 = pk2t(p[14], p[15]);
            lswap(w0, w2, hiw); lswap(w1, w3, hiw);
            lswap(w4, w6, hiw); lswap(w5, w7, hiw);
            union { unsigned int u[4]; bf8 v; } P0, P1;
            P0.u[0] = w0; P0.u[1] = w1; P0.u[2] = w2; P0.u[3] = w3;
            P1.u[0] = w4; P1.u[1] = w5; P1.u[2] = w6; P1.u[3] = w7;
            o = __builtin_amdgcn_mfma_f32_32x32x16_bf16(vt[0], P0.v, o, 0, 0, 0);
            o = __builtin_amdgcn_mfma_f32_32x32x16_bf16(vt[1], P1.v, o, 0, 0, 0);
        }
        if (c < 3) { STAGE_WRITE((c + 1) & 1); }
        __syncthreads();
    }
    #undef STAGE_LOAD
    #undef STAGE_WRITE

    // epilogue: O^T regs -> LDS (swizzled, 16 KB) -> coalesced global
    {
        float inv = 1.0f / lreg;
        int ql = wid * 32 + lq;            // 0..255 (block-local q)
        #pragma unroll
        for (int b4 = 0; b4 < 4; ++b4) {
            short4 pkv;
            pkv.x = f2bs(o[b4 * 4 + 0] * inv);
            pkv.y = f2bs(o[b4 * 4 + 1] * inv);
            pkv.z = f2bs(o[b4 * 4 + 2] * inv);
            pkv.w = f2bs(o[b4 * 4 + 3] * inv);
            int dbyte = (8 * b4 + 4 * lg) * 2;
            *(short4*)(lds + ql * 64 + (dbyte ^ ((ql & 7) << 3))) = pkv;
        }
    }
    __syncthreads();
    {
        int row  = tid >> 1;                // 0..255
        int pbase = (tid & 1) * 4;          // 0 or 4
        short* dst = ctx + (size_t)(b * 512 + half * 256 + row) * 128 + h * 32;
        #pragma unroll
        for (int i = 0; i < 4; ++i) {
            int part = pbase + i;           // 0..7
            short4 pv = *(short4*)(lds + row * 64 + ((part * 8) ^ ((row & 7) << 3)));
            *(short4*)(dst + part * 4) = pv;
        }
    }
}

// ---------------------------------------------------------------------------
// k6: FUSED out_proj+combine+FFN+finalBN (R11-proven). 512 blocks.
// ---------------------------------------------------------------------------
__global__ __launch_bounds__(256)
void outproj_ff_kernel(const short* __restrict__ ctxb, const short* __restrict__ wbf,
                       const float* __restrict__ bout,
                       const short* __restrict__ hin1b, const short* __restrict__ hlocb,
                       const float* __restrict__ g1a, const float* __restrict__ b1a,
                       const float* __restrict__ b1, const float* __restrict__ b2,
                       const float* __restrict__ g2, const float* __restrict__ b2g,
                       float* __restrict__ out)
{
    __shared__ __align__(16) short ldsH[64 * 128];   // 16 KB, byte ^ ((row&7)<<4)
    __shared__ __align__(16) short ldsF[64 * 256];   // 32 KB, byte ^ ((row&7)<<4)
    const int my = blockIdx.x;
    const int lane = threadIdx.x & 63;
    const int wid  = threadIdx.x >> 6;
    const int lrow = lane & 15;
    const int lk   = (lane >> 4) * 8;
    const int rbase = (lane >> 4) * 4;
    const float rs = 0.9999950000374998f;

    // ---- phase 0: out_proj + combine -> ldsH ----
    {
        const int m0 = (wid >> 1) * 32;
        const int n0 = (wid & 1) * 64;
        f32x4 acc[2][4] = {};
        const short* Ap = ctxb + (size_t)(my * 64 + m0 + lrow) * 128 + lk;
        const short* Wp = wbf + 131072 + (size_t)(n0 + lrow) * 128 + lk;
        #pragma unroll
        for (int ks = 0; ks < 128; ks += 32) {
            bf8 af[2], wf[4];
            af[0] = *(const bf8*)(Ap + ks);
            af[1] = *(const bf8*)(Ap + 16 * 128 + ks);
            #pragma unroll
            for (int j = 0; j < 4; ++j) wf[j] = *(const bf8*)(Wp + (size_t)j * 16 * 128 + ks);
            #pragma unroll
            for (int i = 0; i < 2; ++i)
                #pragma unroll
                for (int j = 0; j < 4; ++j)
                    acc[i][j] = __builtin_amdgcn_mfma_f32_16x16x32_bf16(af[i], wf[j], acc[i][j], 0, 0, 0);
        }
        #pragma unroll
        for (int j = 0; j < 4; ++j) {
            int col = n0 + j * 16 + lrow;            // 0..127
            float bcol = bout[col];
            float gsc = g1a[col] * rs;
            float bsc = b1a[col];
            #pragma unroll
            for (int i = 0; i < 2; ++i)
                #pragma unroll
                for (int r = 0; r < 4; ++r) {
                    int rl = m0 + i * 16 + rbase + r;
                    size_t idx = (size_t)(my * 64 + rl) * 128 + col;
                    float v = acc[i][j][r] + bcol;
                    float o = bs1f(hlocb[idx]) + (bs1f(hin1b[idx]) + v) * gsc + bsc;
                    int byte = (rl * 256 + col * 2) ^ ((rl & 7) << 4);
                    *(short*)((char*)ldsH + byte) = f2bs(o);
                }
        }
    }
    __syncthreads();
    // ---- phase 1: ff1 -> ldsF ----
    {
        const int m0 = (wid >> 1) * 32;
        const int n0 = (wid & 1) * 128;
        f32x4 acc[2][8] = {};
        const short* Wp = wbf + 147456 + (size_t)(n0 + lrow) * 128 + lk;
        #pragma unroll
        for (int ks = 0; ks < 128; ks += 32) {
            bf8 af[2], wf[8];
            #pragma unroll
            for (int i = 0; i < 2; ++i) {
                int row = m0 + lrow + i * 16;
                int byte = (row * 256 + (ks + lk) * 2) ^ ((row & 7) << 4);
                af[i] = *(const bf8*)((const char*)ldsH + byte);
            }
            #pragma unroll
            for (int j = 0; j < 8; ++j) wf[j] = *(const bf8*)(Wp + (size_t)j * 16 * 128 + ks);
            #pragma unroll
            for (int i = 0; i < 2; ++i)
                #pragma unroll
                for (int j = 0; j < 8; ++j)
                    acc[i][j] = __builtin_amdgcn_mfma_f32_16x16x32_bf16(af[i], wf[j], acc[i][j], 0, 0, 0);
        }
        #pragma unroll
        for (int j = 0; j < 8; ++j) {
            int col = n0 + j * 16 + lrow;            // 0..255
            float bc = b1[col];
            #pragma unroll
            for (int i = 0; i < 2; ++i)
                #pragma unroll
                for (int r = 0; r < 4; ++r) {
                    int rl = m0 + i * 16 + rbase + r;
                    float v = fmaxf(acc[i][j][r] + bc, 0.f);
                    int byte = (rl * 512 + col * 2) ^ ((rl & 7) << 4);
                    *(short*)((char*)ldsF + byte) = f2bs(v);
                }
        }
    }
    __syncthreads();
    // ---- phase 2: ff2 + final BN (residual from ldsH) ----
    {
        const int m0 = (wid >> 1) * 32;
        const int n0 = (wid & 1) * 64;
        f32x4 acc[2][4] = {};
        const short* Wp = wbf + 180224 + (size_t)(n0 + lrow) * 256 + lk;
        #pragma unroll
        for (int ks = 0; ks < 256; ks += 32) {
            bf8 af[2], wf[4];
            #pragma unroll
            for (int i = 0; i < 2; ++i) {
                int row = m0 + lrow + i * 16;
                int byte = (row * 512 + (ks + lk) * 2) ^ ((row & 7) << 4);
                af[i] = *(const bf8*)((const char*)ldsF + byte);
            }
            #pragma unroll
            for (int j = 0; j < 4; ++j) wf[j] = *(const bf8*)(Wp + (size_t)j * 16 * 256 + ks);
            #pragma unroll
            for (int i = 0; i < 2; ++i)
                #pragma unroll
                for (int j = 0; j < 4; ++j)
                    acc[i][j] = __builtin_amdgcn_mfma_f32_16x16x32_bf16(af[i], wf[j], acc[i][j], 0, 0, 0);
        }
        #pragma unroll
        for (int j = 0; j < 4; ++j) {
            int col = n0 + j * 16 + lrow;
            float bc = b2[col];
            float gsc = g2[col] * rs;
            float bsc = b2g[col];
            #pragma unroll
            for (int i = 0; i < 2; ++i)
                #pragma unroll
                for (int r = 0; r < 4; ++r) {
                    int rl = m0 + i * 16 + rbase + r;
                    int hbyte = (rl * 256 + col * 2) ^ ((rl & 7) << 4);
                    float hres = bs1f(*(const short*)((const char*)ldsH + hbyte));
                    float v = acc[i][j][r] + bc;
                    out[(size_t)(my * 64 + rl) * 128 + col] = (hres + v) * gsc + bsc;
                }
        }
    }
}

// ---------------------------------------------------------------------------
extern "C" void kernel_launch(void* const* d_in, const int* in_sizes, int n_in,
                              void* d_out, int out_size, void* d_ws, size_t ws_size,
                              hipStream_t stream)
{
    (void)in_sizes; (void)n_in; (void)out_size; (void)ws_size;

    const float* x    = (const float*)d_in[0];
    const int*   ei   = (const int*)d_in[1];
    const float* Wres = (const float*)d_in[3];
    const float* bres = (const float*)d_in[4];
    const float* Wk   = (const float*)d_in[5];
    const float* bk   = (const float*)d_in[6];
    const float* Wq   = (const float*)d_in[7];
    const float* bq   = (const float*)d_in[8];
    const float* Wv   = (const float*)d_in[9];
    const float* bv   = (const float*)d_in[10];
    const float* Wsk  = (const float*)d_in[11];
    const float* bsk  = (const float*)d_in[12];
    const float* g1l  = (const float*)d_in[13];
    const float* b1l  = (const float*)d_in[14];
    const float* g1a  = (const float*)d_in[15];
    const float* b1a  = (const float*)d_in[16];
    const float* Win  = (const float*)d_in[17];
    const float* bin  = (const float*)d_in[18];
    const float* Wout = (const float*)d_in[19];
    const float* bout = (const float*)d_in[20];
    const float* W1   = (const float*)d_in[21];
    const float* b1   = (const float*)d_in[22];
    const float* W2   = (const float*)d_in[23];
    const float* b2   = (const float*)d_in[24];
    const float* g2   = (const float*)d_in[25];
    const float* b2g  = (const float*)d_in[26];
    float* out = (float*)d_out;

    float* ws = (float*)d_ws;
    // ----- workspace layout (float-slot offsets), lifetimes k0..k6 -----
    short* hin1b = (short*)ws;                        // [0,0.5NM)  w:k2 r:k3,k4,k6
    short* kbv   = (short*)(ws + NM / 2);             // [0.5NM,NM) w:k2 r:k4
    short* qvb   = (short*)(ws + NM);                 // [NM,2NM)   w:k2 r:k4 (q,v ilv)
    short* skipb = (short*)(ws + 2 * NM);             // [2NM,2.5NM) w:k2 r:k4
    short* xb    = (short*)(ws + 2 * NM + NM / 2);    // [2.5NM,3NM) w:k1 r:k2
    short* qkvb  = (short*)(ws + 3 * NM);             // [3NM,4.5NM) w:k3 r:k5
    short* hlocb = (short*)(ws + 4 * NM + NM / 2);    // [4.5NM,5NM) w:k4 r:k6
    // slot ints/ushorts overlay [5NM, ...) — dead after k4; ctxb (w:k5) reuses it
    int* deg = (int*)(ws + 5 * NM);                   // [N] w:k0, rmw:k1 r:k4
    unsigned short* slots = (unsigned short*)(deg + N_NODES);  // [N*CAP] w:k1 r:k4
    short* ctxb  = (short*)(ws + 5 * NM);             // [5NM,5.5NM) w:k5 r:k6
    short* wbf   = (short*)(ws + 6 * NM);             // 212992 shorts = 106496 fslots
    float* bcat  = ws + 6 * NM + 106496;              // [640] f32
    // total extent: 6NM + 107136 floats ≈ 101.1 MB

    dim3 blk(256);
    // 1/sqrt(32) * log2(e)  (exp2-domain softmax)
    const float qscale = 0.17677669529663687f * 1.4426950408889634f;

    // 0. zero deg
    zero_deg_kernel<<<dim3(32), blk, 0, stream>>>((int4*)deg);

    // 1. scatter (first) + cvt
    cvt_scatter_kernel<<<dim3(6353), blk, 0, stream>>>(
        x, Wres, Wk, Wq, Wv, Wsk, Win, Wout, W1, W2,
        bres, bk, bq, bv, bsk, ei, xb, wbf, bcat, deg, slots);

    // 2. proj5 GEMM (merged 5 groups)
    proj5_kernel<<<dim3(512), blk, 0, stream>>>(
        xb, wbf, bcat, hin1b, kbv, (unsigned int*)qvb, skipb);

    // 3. in_proj GEMM (merged 3 groups)
    inproj_kernel<<<dim3(512), blk, 0, stream>>>(
        hin1b, wbf, bin, qkvb, qscale);

    // 4. gather + skip + BN (slot lists)
    gather_local_kernel<<<dim3(N_NODES / 4), blk, 0, stream>>>(
        (const unsigned int*)kbv, (const uint2*)qvb, (const unsigned int*)skipb,
        (const unsigned int*)hin1b, deg, slots, g1l, b1l,
        (unsigned int*)hlocb);

    // 5. attention (512 blocks x 512 thr, 2 blocks/CU; trunc P-pack)
    attn_mfma<<<dim3(512), dim3(512), 0, stream>>>(qkvb, ctxb);

    // 6. fused out_proj + combine + FFN + final BN
    outproj_ff_kernel<<<dim3(512), blk, 0, stream>>>(
        ctxb, wbf, bout, hin1b, hlocb, g1a, b1a, b1, b2, g2, b2g, out);
}

// Round 24
// 182.163 us; speedup vs baseline: 1.0097x; 1.0018x over previous
//
#include <hip/hip_runtime.h>
#include <math.h>

#define N_NODES 32768
#define N_EDGES 524288
#define DIM     128
#define CAP     80

static constexpr size_t NM = (size_t)N_NODES * DIM;   // 4194304

typedef __attribute__((ext_vector_type(8)))  short bf8;     // 8 bf16
typedef __attribute__((ext_vector_type(4)))  float f32x4;
typedef __attribute__((ext_vector_type(16))) float f32x16;

__device__ __forceinline__ short f2bs(float x) {
    union { float f; unsigned int u; } v; v.f = x;
    unsigned int r = v.u + 0x7fffu + ((v.u >> 16) & 1u);
    return (short)(r >> 16);
}
__device__ __forceinline__ unsigned int pk2(float a, float b) {
    return (unsigned int)(unsigned short)f2bs(a) |
           ((unsigned int)(unsigned short)f2bs(b) << 16);
}
// truncation pack (P in (0,1]: rel err <= 2^-8, cheap: 3 ops)
__device__ __forceinline__ unsigned int pk2t(float a, float b) {
    union { float f; unsigned int u; } ua, ub; ua.f = a; ub.f = b;
    return (ua.u >> 16) | (ub.u & 0xffff0000u);
}
__device__ __forceinline__ float2 bs2f(unsigned int u) {
    union { unsigned int a; float f; } lo, hi;
    lo.a = u << 16; hi.a = u & 0xffff0000u;
    float2 r; r.x = lo.f; r.y = hi.f; return r;
}
__device__ __forceinline__ float bs1f(short s) {
    union { unsigned int a; float f; } t;
    t.a = ((unsigned int)(unsigned short)s) << 16; return t.f;
}

// ---------------------------------------------------------------------------
// k0: zero deg.
// ---------------------------------------------------------------------------
__global__ __launch_bounds__(256)
void zero_deg_kernel(int4* __restrict__ deg4)
{
    deg4[blockIdx.x * 256 + threadIdx.x] = make_int4(0, 0, 0, 0);  // 8192 int4
}

// ---------------------------------------------------------------------------
// k1: scatter + cvt (R13-proven). blocks [0,2048): slot scatter first;
// [2048,6353): x->bf16, weights->wbf, biases->bcat.
// ---------------------------------------------------------------------------
__global__ __launch_bounds__(256)
void cvt_scatter_kernel(const float* __restrict__ x,
                        const float* __restrict__ w0, const float* __restrict__ w1,
                        const float* __restrict__ w2, const float* __restrict__ w3,
                        const float* __restrict__ w4, const float* __restrict__ w5,
                        const float* __restrict__ w6, const float* __restrict__ w7,
                        const float* __restrict__ w8,
                        const float* __restrict__ b0, const float* __restrict__ b1,
                        const float* __restrict__ b2, const float* __restrict__ b3,
                        const float* __restrict__ b4,
                        const int* __restrict__ ei,
                        short* __restrict__ xb, short* __restrict__ wbf,
                        float* __restrict__ bcat,
                        int* __restrict__ deg, unsigned short* __restrict__ slots)
{
    if (blockIdx.x < 2048) {
        int e = blockIdx.x * 256 + threadIdx.x;            // 0..524287
        int d = ei[N_EDGES + e];
        int pos = atomicAdd(&deg[d], 1);
        if (pos < CAP) slots[d * CAP + pos] = (unsigned short)ei[e];
        return;
    }
    long long t = (long long)(blockIdx.x - 2048) * 256 + threadIdx.x;
    long long i4 = t * 4;
    if (i4 < (long long)NM) {
        float4 v = *(const float4*)(x + i4);
        short4 o; o.x = f2bs(v.x); o.y = f2bs(v.y); o.z = f2bs(v.z); o.w = f2bs(v.w);
        *(short4*)(xb + i4) = o;
    } else {
        int j = (int)(i4 - (long long)NM);
        if (j < 212992) {
            const float* src; int off;
            if      (j <  16384) { src = w0; off = 0; }
            else if (j <  32768) { src = w1; off = 16384; }
            else if (j <  49152) { src = w2; off = 32768; }
            else if (j <  65536) { src = w3; off = 49152; }
            else if (j <  81920) { src = w4; off = 65536; }
            else if (j < 131072) { src = w5; off = 81920; }
            else if (j < 147456) { src = w6; off = 131072; }
            else if (j < 180224) { src = w7; off = 147456; }
            else                 { src = w8; off = 180224; }
            float4 v = *(const float4*)(src + (j - off));
            short4 o; o.x = f2bs(v.x); o.y = f2bs(v.y); o.z = f2bs(v.z); o.w = f2bs(v.w);
            *(short4*)(wbf + j) = o;
        } else if (j < 213632) {
            int jb = j - 212992;                 // 0..639
            int grp = jb >> 7, loc = jb & 127;
            const float* bs = (grp == 0) ? b0 : (grp == 1) ? b1 :
                              (grp == 2) ? b2 : (grp == 3) ? b3 : b4;
            float4 v = *(const float4*)(bs + loc);
            *(float4*)(bcat + jb) = v;
        }
    }
}

// ---------------------------------------------------------------------------
// k2: proj5 MERGED (R16-proven). One block (64 rows), all 5 projections.
// ---------------------------------------------------------------------------
__global__ __launch_bounds__(256)
void proj5_kernel(const short* __restrict__ xb, const short* __restrict__ wbf,
                  const float* __restrict__ bcat,
                  short* __restrict__ hin1b, short* __restrict__ kbv,
                  unsigned int* __restrict__ qvu, short* __restrict__ skipb)
{
    const int my = blockIdx.x;            // 0..511
    const int lane = threadIdx.x & 63;
    const int wid  = threadIdx.x >> 6;
    const int m0 = my * 64 + (wid >> 1) * 32;
    const int n0 = (wid & 1) * 64;
    const int lrow = lane & 15;
    const int lk   = (lane >> 4) * 8;

    bf8 af[2][4];
    const short* Ap = xb + (size_t)(m0 + lrow) * 128 + lk;
    #pragma unroll
    for (int i = 0; i < 2; ++i)
        #pragma unroll
        for (int ks = 0; ks < 4; ++ks)
            af[i][ks] = *(const bf8*)(Ap + (size_t)i * 16 * 128 + ks * 32);

    f32x4 acc[5][2][4] = {};
    #pragma unroll
    for (int ks = 0; ks < 4; ++ks) {
        #pragma unroll
        for (int g = 0; g < 5; ++g) {
            bf8 wf[4];
            const short* Wp = wbf + g * 16384 + (size_t)(n0 + lrow) * 128 + ks * 32 + lk;
            #pragma unroll
            for (int j = 0; j < 4; ++j)
                wf[j] = *(const bf8*)(Wp + (size_t)j * 16 * 128);
            #pragma unroll
            for (int i = 0; i < 2; ++i)
                #pragma unroll
                for (int j = 0; j < 4; ++j)
                    acc[g][i][j] = __builtin_amdgcn_mfma_f32_16x16x32_bf16(
                                       af[i][ks], wf[j], acc[g][i][j], 0, 0, 0);
        }
    }

    const int rbase = (lane >> 4) * 4;
    #pragma unroll
    for (int j = 0; j < 4; ++j) {
        int col = n0 + j * 16 + lrow;                 // 0..127
        float b0c = bcat[col],       b1c = bcat[128 + col];
        float b2c = bcat[256 + col], b3c = bcat[384 + col];
        float b4c = bcat[512 + col];
        #pragma unroll
        for (int i = 0; i < 2; ++i)
            #pragma unroll
            for (int r = 0; r < 4; ++r) {
                int row = m0 + i * 16 + rbase + r;
                size_t ridx = (size_t)row * 128 + col;
                hin1b[ridx] = f2bs(fmaxf(acc[0][i][j][r] + b0c, 0.f));
                kbv[ridx]   = f2bs(acc[1][i][j][r] + b1c);
                qvu[ridx]   = pk2(acc[2][i][j][r] + b2c, acc[3][i][j][r] + b3c);
                skipb[ridx] = f2bs(acc[4][i][j][r] + b4c);
            }
    }
}

// ---------------------------------------------------------------------------
// k3: in_proj MERGED — one block (64 rows) computes all 3 output groups
// (q|k|v cols 0..383). A loaded once; acc[3][2][4]; q pre-scaled. 512 blocks.
// ---------------------------------------------------------------------------
__global__ __launch_bounds__(256)
void inproj_kernel(const short* __restrict__ hin1b, const short* __restrict__ wbf,
                   const float* __restrict__ bin, short* __restrict__ qkvb,
                   float qscale)
{
    const int my = blockIdx.x;            // 0..511
    const int lane = threadIdx.x & 63;
    const int wid  = threadIdx.x >> 6;
    const int m0 = my * 64 + (wid >> 1) * 32;
    const int n0 = (wid & 1) * 64;
    const int lrow = lane & 15;
    const int lk   = (lane >> 4) * 8;

    bf8 af[2][4];
    const short* Ap = hin1b + (size_t)(m0 + lrow) * 128 + lk;
    #pragma unroll
    for (int i = 0; i < 2; ++i)
        #pragma unroll
        for (int ks = 0; ks < 4; ++ks)
            af[i][ks] = *(const bf8*)(Ap + (size_t)i * 16 * 128 + ks * 32);

    f32x4 acc[3][2][4] = {};
    #pragma unroll
    for (int ks = 0; ks < 4; ++ks) {
        #pragma unroll
        for (int g = 0; g < 3; ++g) {
            bf8 wf[4];
            const short* Wp = wbf + 81920 + (size_t)(g * 128 + n0 + lrow) * 128
                              + ks * 32 + lk;
            #pragma unroll
            for (int j = 0; j < 4; ++j)
                wf[j] = *(const bf8*)(Wp + (size_t)j * 16 * 128);
            #pragma unroll
            for (int i = 0; i < 2; ++i)
                #pragma unroll
                for (int j = 0; j < 4; ++j)
                    acc[g][i][j] = __builtin_amdgcn_mfma_f32_16x16x32_bf16(
                                       af[i][ks], wf[j], acc[g][i][j], 0, 0, 0);
        }
    }

    const int rbase = (lane >> 4) * 4;
    #pragma unroll
    for (int g = 0; g < 3; ++g) {
        float sc = (g == 0) ? qscale : 1.0f;
        #pragma unroll
        for (int j = 0; j < 4; ++j) {
            int col = g * 128 + n0 + j * 16 + lrow;   // 0..383
            float bcol = bin[col];
            #pragma unroll
            for (int i = 0; i < 2; ++i)
                #pragma unroll
                for (int r = 0; r < 4; ++r) {
                    int row = m0 + i * 16 + rbase + r;
                    float v = (acc[g][i][j][r] + bcol) * sc;
                    qkvb[(size_t)row * 384 + col] = f2bs(v);
                }
        }
    }
}

// ---------------------------------------------------------------------------
// k4: gather via slot lists (R16-proven). One wave/node, 8-edge unroll.
// ---------------------------------------------------------------------------
__global__ __launch_bounds__(256)
void gather_local_kernel(const unsigned int* __restrict__ kbu,
                         const uint2* __restrict__ qvu,
                         const unsigned int* __restrict__ skipu,
                         const unsigned int* __restrict__ hin1u,
                         const int* __restrict__ deg,
                         const unsigned short* __restrict__ slots,
                         const float* __restrict__ g, const float* __restrict__ beta,
                         unsigned int* __restrict__ hlocal_u)
{
    const int d    = blockIdx.x * 4 + (threadIdx.x >> 6);
    const int lane = threadIdx.x & 63;          // owns cols 2l, 2l+1
    const float rs = 0.9999950000374998f;       // 1/sqrt(1+1e-5)

    float2 k2 = bs2f(kbu[(size_t)d * 64 + lane]);
    int dg = deg[d]; if (dg > CAP) dg = CAP;
    const unsigned short* sp = slots + (size_t)d * CAP;
    int i = 0;

    float ax = 0.f, ay = 0.f, cx = 0.f, cy = 0.f;
    for (; i + 8 <= dg; i += 8) {
        int s[8];
        #pragma unroll
        for (int u = 0; u < 8; ++u) s[u] = sp[i + u];
        uint2 w[8];
        #pragma unroll
        for (int u = 0; u < 8; ++u) w[u] = qvu[(size_t)s[u] * 64 + lane];
        #pragma unroll
        for (int u = 0; u < 8; ++u) {
            float2 pa = bs2f(w[u].x), pb = bs2f(w[u].y);
            if (u & 1) {
                cx += pa.y * __builtin_amdgcn_rcpf(1.0f + __expf(-(k2.x + pa.x)));
                cy += pb.y * __builtin_amdgcn_rcpf(1.0f + __expf(-(k2.y + pb.x)));
            } else {
                ax += pa.y * __builtin_amdgcn_rcpf(1.0f + __expf(-(k2.x + pa.x)));
                ay += pb.y * __builtin_amdgcn_rcpf(1.0f + __expf(-(k2.y + pb.x)));
            }
        }
    }
    for (; i + 4 <= dg; i += 4) {
        int s0 = sp[i], s1 = sp[i + 1], s2 = sp[i + 2], s3 = sp[i + 3];
        uint2 w0 = qvu[(size_t)s0 * 64 + lane];
        uint2 w1 = qvu[(size_t)s1 * 64 + lane];
        uint2 w2 = qvu[(size_t)s2 * 64 + lane];
        uint2 w3 = qvu[(size_t)s3 * 64 + lane];
        float2 p0 = bs2f(w0.x), p1 = bs2f(w0.y);
        float2 p2 = bs2f(w1.x), p3 = bs2f(w1.y);
        float2 p4 = bs2f(w2.x), p5 = bs2f(w2.y);
        float2 p6 = bs2f(w3.x), p7 = bs2f(w3.y);
        ax += p0.y * __builtin_amdgcn_rcpf(1.0f + __expf(-(k2.x + p0.x)));
        ay += p1.y * __builtin_amdgcn_rcpf(1.0f + __expf(-(k2.y + p1.x)));
        cx += p2.y * __builtin_amdgcn_rcpf(1.0f + __expf(-(k2.x + p2.x)));
        cy += p3.y * __builtin_amdgcn_rcpf(1.0f + __expf(-(k2.y + p3.x)));
        ax += p4.y * __builtin_amdgcn_rcpf(1.0f + __expf(-(k2.x + p4.x)));
        ay += p5.y * __builtin_amdgcn_rcpf(1.0f + __expf(-(k2.y + p5.x)));
        cx += p6.y * __builtin_amdgcn_rcpf(1.0f + __expf(-(k2.x + p6.x)));
        cy += p7.y * __builtin_amdgcn_rcpf(1.0f + __expf(-(k2.y + p7.x)));
    }
    for (; i < dg; ++i) {
        int s0 = sp[i];
        uint2 w0 = qvu[(size_t)s0 * 64 + lane];
        float2 p0 = bs2f(w0.x), p1 = bs2f(w0.y);
        ax += p0.y * __builtin_amdgcn_rcpf(1.0f + __expf(-(k2.x + p0.x)));
        ay += p1.y * __builtin_amdgcn_rcpf(1.0f + __expf(-(k2.y + p1.x)));
    }
    ax += cx; ay += cy;

    float2 sk = bs2f(skipu[(size_t)d * 64 + lane]);
    float2 hi = bs2f(hin1u[(size_t)d * 64 + lane]);
    float2 gv = *(const float2*)(g + lane * 2);
    float2 bt = *(const float2*)(beta + lane * 2);
    float ox = (hi.x + sk.x + ax) * (gv.x * rs) + bt.x;
    float oy = (hi.y + sk.y + ay) * (gv.y * rs) + bt.y;
    hlocal_u[(size_t)d * 64 + lane] = pk2(ox, oy);
}

// ---------------------------------------------------------------------------
// k5: MFMA flash attention (R16-proven). 512 blocks = (b,h,half), 512 thr
// (8 waves, 32 q-rows each). Chunked dbuf K/V staging; exp2 softmax;
// truncation P-pack.
// ---------------------------------------------------------------------------
__device__ __forceinline__ void lswap(unsigned int& X, unsigned int& Y, bool hi) {
    unsigned int Xs = (unsigned int)__shfl_xor((int)X, 32);
    unsigned int Ys = (unsigned int)__shfl_xor((int)Y, 32);
    unsigned int Xn = hi ? Ys : X;
    unsigned int Yn = hi ? Y  : Xs;
    X = Xn; Y = Yn;
}

__global__ __launch_bounds__(512)
void attn_mfma(const short* __restrict__ qkv, short* __restrict__ ctx)
{
    __shared__ __align__(16) char lds[36864];
    // carve: K buf s at lds + s*10240 (128 keys x 40 shorts);
    //        V^T buf s at lds + 20480 + s*8192 (32 rows x 256 B, swizzled)

    const int blk  = blockIdx.x;         // B*H*2 = 512
    const int half = blk & 1;
    const int h    = (blk >> 1) & 3;
    const int b    = blk >> 3;
    const int tid  = threadIdx.x;        // 0..511
    const int lane = tid & 63;
    const int wid  = tid >> 6;           // 0..7
    const int lq = lane & 31;
    const int lg = lane >> 5;
    const size_t gbase = (size_t)(b * 512) * 384 + h * 32;

    const int skey  = tid >> 2;          // 0..127
    const int spart = tid & 3;
    const int vp    = tid & 63;
    const int vdq   = tid >> 6;

    bf8    kst;
    short4 v0s, v1s;

    #define STAGE_LOAD(ck)                                                     \
        kst = *(const bf8*)(qkv + gbase +                                      \
                (size_t)((ck) * 128 + skey) * 384 + 128 + spart * 8);          \
        {                                                                      \
            const short* vr = qkv + gbase +                                    \
                (size_t)((ck) * 128 + 2 * vp) * 384 + 256 + vdq * 4;           \
            v0s = *(const short4*)(vr);                                        \
            v1s = *(const short4*)(vr + 384);                                  \
        }

    #define STAGE_WRITE(s)                                                     \
        *(bf8*)((short*)(lds + (s) * 10240) + skey * 40 + spart * 8) = kst;    \
        {                                                                      \
            char* vb = lds + 20480 + (s) * 8192;                               \
            short v0a[4] = {v0s.x, v0s.y, v0s.z, v0s.w};                       \
            short v1a[4] = {v1s.x, v1s.y, v1s.z, v1s.w};                       \
            _Pragma("unroll")                                                  \
            for (int j = 0; j < 4; ++j) {                                      \
                int d = vdq * 4 + j;                                           \
                unsigned int w = (unsigned int)(unsigned short)v0a[j] |        \
                                 ((unsigned int)(unsigned short)v1a[j] << 16); \
                *(unsigned int*)(vb + d * 256 + ((4 * vp) ^ ((d & 7) << 4))) = w; \
            }                                                                  \
        }

    const int qoff = half * 256 + wid * 32;
    bf8 qf[2];
    #pragma unroll
    for (int kh = 0; kh < 2; ++kh)
        qf[kh] = *(const bf8*)(qkv + gbase +
                       (size_t)(qoff + lq) * 384 + kh * 16 + lg * 8);

    const f32x16 Z16 = {0.f,0.f,0.f,0.f,0.f,0.f,0.f,0.f,0.f,0.f,0.f,0.f,0.f,0.f,0.f,0.f};
    f32x16 o = Z16;
    float mreg = -1e30f;
    float lreg = 0.f;
    const bool hiw = (lg != 0);

    STAGE_LOAD(0);
    STAGE_WRITE(0);
    __syncthreads();

    for (int c = 0; c < 4; ++c) {
        if (c < 3) { STAGE_LOAD(c + 1); }
        const short* Kb = (const short*)(lds + (c & 1) * 10240);
        const char*  Vb = lds + 20480 + (c & 1) * 8192;

        #pragma unroll
        for (int ktl = 0; ktl < 4; ++ktl) {
            bf8 ak[2], vt[2];
            #pragma unroll
            for (int kh = 0; kh < 2; ++kh) {
                ak[kh] = *(const bf8*)(Kb + (ktl * 32 + lq) * 40 + kh * 16 + lg * 8);
                int kbyte = (ktl * 32 + kh * 16 + lg * 8) * 2;   // 0..254
                vt[kh] = *(const bf8*)(Vb + lq * 256 + (kbyte ^ ((lq & 7) << 4)));
            }
            f32x16 s = Z16;
            s = __builtin_amdgcn_mfma_f32_32x32x16_bf16(ak[0], qf[0], s, 0, 0, 0);
            s = __builtin_amdgcn_mfma_f32_32x32x16_bf16(ak[1], qf[1], s, 0, 0, 0);
            float t0 = fmaxf(fmaxf(s[0],  s[1]),  s[2]);
            float t1 = fmaxf(fmaxf(s[3],  s[4]),  s[5]);
            float t2 = fmaxf(fmaxf(s[6],  s[7]),  s[8]);
            float t3 = fmaxf(fmaxf(s[9],  s[10]), s[11]);
            float t4 = fmaxf(fmaxf(s[12], s[13]), s[14]);
            float mt = fmaxf(fmaxf(fmaxf(t0, t1), t2), fmaxf(fmaxf(t3, t4), s[15]));
            mt = fmaxf(mt, __shfl_xor(mt, 32));
            if (__any(mt > mreg + 11.5415603f)) {    // defer-max, log2 domain
                float mnew = fmaxf(mreg, mt);
                float corr = exp2f(mreg - mnew);
                mreg = mnew;
                lreg *= corr;
                #pragma unroll
                for (int r = 0; r < 16; ++r) o[r] *= corr;
            }
            float m = mreg;
            float p[16]; float ps = 0.f;
            #pragma unroll
            for (int r = 0; r < 16; ++r) { p[r] = exp2f(s[r] - m); ps += p[r]; }
            ps += __shfl_xor(ps, 32);
            lreg += ps;
            unsigned int w0 = pk2t(p[0],  p[1]),  w1 = pk2t(p[2],  p[3]);
            unsigned int w2 = pk2t(p[4],  p[5]),  w3 = pk2t(p[6],  p[7]);
            unsigned int w4 = pk2t(p[8],  p[9]),  w5 = pk2t(p[10], p[11]);
            unsigned int w6 = pk2t(p[12], p[13]), w7 = pk2t(p[14], p[15]);
            lswap(w0, w2, hiw); lswap(w1, w3, hiw);
            lswap(w4, w6, hiw); lswap(w5, w7, hiw);
            union { unsigned int u[4]; bf8 v; } P0, P1;
            P0.u[0] = w0; P0.u[1] = w1; P0.u[2] = w2; P0.u[3] = w3;
            P1.u[0] = w4; P1.u[1] = w5; P1.u[2] = w6; P1.u[3] = w7;
            o = __builtin_amdgcn_mfma_f32_32x32x16_bf16(vt[0], P0.v, o, 0, 0, 0);
            o = __builtin_amdgcn_mfma_f32_32x32x16_bf16(vt[1], P1.v, o, 0, 0, 0);
        }
        if (c < 3) { STAGE_WRITE((c + 1) & 1); }
        __syncthreads();
    }
    #undef STAGE_LOAD
    #undef STAGE_WRITE

    // epilogue: O^T regs -> LDS (swizzled, 16 KB) -> coalesced global
    {
        float inv = 1.0f / lreg;
        int ql = wid * 32 + lq;            // 0..255 (block-local q)
        #pragma unroll
        for (int b4 = 0; b4 < 4; ++b4) {
            short4 pkv;
            pkv.x = f2bs(o[b4 * 4 + 0] * inv);
            pkv.y = f2bs(o[b4 * 4 + 1] * inv);
            pkv.z = f2bs(o[b4 * 4 + 2] * inv);
            pkv.w = f2bs(o[b4 * 4 + 3] * inv);
            int dbyte = (8 * b4 + 4 * lg) * 2;
            *(short4*)(lds + ql * 64 + (dbyte ^ ((ql & 7) << 3))) = pkv;
        }
    }
    __syncthreads();
    {
        int row  = tid >> 1;                // 0..255
        int pbase = (tid & 1) * 4;          // 0 or 4
        short* dst = ctx + (size_t)(b * 512 + half * 256 + row) * 128 + h * 32;
        #pragma unroll
        for (int i = 0; i < 4; ++i) {
            int part = pbase + i;           // 0..7
            short4 pv = *(short4*)(lds + row * 64 + ((part * 8) ^ ((row & 7) << 3)));
            *(short4*)(dst + part * 4) = pv;
        }
    }
}

// ---------------------------------------------------------------------------
// k6: FUSED out_proj+combine+FFN+finalBN (R11-proven). 512 blocks.
// ---------------------------------------------------------------------------
__global__ __launch_bounds__(256)
void outproj_ff_kernel(const short* __restrict__ ctxb, const short* __restrict__ wbf,
                       const float* __restrict__ bout,
                       const short* __restrict__ hin1b, const short* __restrict__ hlocb,
                       const float* __restrict__ g1a, const float* __restrict__ b1a,
                       const float* __restrict__ b1, const float* __restrict__ b2,
                       const float* __restrict__ g2, const float* __restrict__ b2g,
                       float* __restrict__ out)
{
    __shared__ __align__(16) short ldsH[64 * 128];   // 16 KB, byte ^ ((row&7)<<4)
    __shared__ __align__(16) short ldsF[64 * 256];   // 32 KB, byte ^ ((row&7)<<4)
    const int my = blockIdx.x;
    const int lane = threadIdx.x & 63;
    const int wid  = threadIdx.x >> 6;
    const int lrow = lane & 15;
    const int lk   = (lane >> 4) * 8;
    const int rbase = (lane >> 4) * 4;
    const float rs = 0.9999950000374998f;

    // ---- phase 0: out_proj + combine -> ldsH ----
    {
        const int m0 = (wid >> 1) * 32;
        const int n0 = (wid & 1) * 64;
        f32x4 acc[2][4] = {};
        const short* Ap = ctxb + (size_t)(my * 64 + m0 + lrow) * 128 + lk;
        const short* Wp = wbf + 131072 + (size_t)(n0 + lrow) * 128 + lk;
        #pragma unroll
        for (int ks = 0; ks < 128; ks += 32) {
            bf8 af[2], wf[4];
            af[0] = *(const bf8*)(Ap + ks);
            af[1] = *(const bf8*)(Ap + 16 * 128 + ks);
            #pragma unroll
            for (int j = 0; j < 4; ++j) wf[j] = *(const bf8*)(Wp + (size_t)j * 16 * 128 + ks);
            #pragma unroll
            for (int i = 0; i < 2; ++i)
                #pragma unroll
                for (int j = 0; j < 4; ++j)
                    acc[i][j] = __builtin_amdgcn_mfma_f32_16x16x32_bf16(af[i], wf[j], acc[i][j], 0, 0, 0);
        }
        #pragma unroll
        for (int j = 0; j < 4; ++j) {
            int col = n0 + j * 16 + lrow;            // 0..127
            float bcol = bout[col];
            float gsc = g1a[col] * rs;
            float bsc = b1a[col];
            #pragma unroll
            for (int i = 0; i < 2; ++i)
                #pragma unroll
                for (int r = 0; r < 4; ++r) {
                    int rl = m0 + i * 16 + rbase + r;
                    size_t idx = (size_t)(my * 64 + rl) * 128 + col;
                    float v = acc[i][j][r] + bcol;
                    float o = bs1f(hlocb[idx]) + (bs1f(hin1b[idx]) + v) * gsc + bsc;
                    int byte = (rl * 256 + col * 2) ^ ((rl & 7) << 4);
                    *(short*)((char*)ldsH + byte) = f2bs(o);
                }
        }
    }
    __syncthreads();
    // ---- phase 1: ff1 -> ldsF ----
    {
        const int m0 = (wid >> 1) * 32;
        const int n0 = (wid & 1) * 128;
        f32x4 acc[2][8] = {};
        const short* Wp = wbf + 147456 + (size_t)(n0 + lrow) * 128 + lk;
        #pragma unroll
        for (int ks = 0; ks < 128; ks += 32) {
            bf8 af[2], wf[8];
            #pragma unroll
            for (int i = 0; i < 2; ++i) {
                int row = m0 + lrow + i * 16;
                int byte = (row * 256 + (ks + lk) * 2) ^ ((row & 7) << 4);
                af[i] = *(const bf8*)((const char*)ldsH + byte);
            }
            #pragma unroll
            for (int j = 0; j < 8; ++j) wf[j] = *(const bf8*)(Wp + (size_t)j * 16 * 128 + ks);
            #pragma unroll
            for (int i = 0; i < 2; ++i)
                #pragma unroll
                for (int j = 0; j < 8; ++j)
                    acc[i][j] = __builtin_amdgcn_mfma_f32_16x16x32_bf16(af[i], wf[j], acc[i][j], 0, 0, 0);
        }
        #pragma unroll
        for (int j = 0; j < 8; ++j) {
            int col = n0 + j * 16 + lrow;            // 0..255
            float bc = b1[col];
            #pragma unroll
            for (int i = 0; i < 2; ++i)
                #pragma unroll
                for (int r = 0; r < 4; ++r) {
                    int rl = m0 + i * 16 + rbase + r;
                    float v = fmaxf(acc[i][j][r] + bc, 0.f);
                    int byte = (rl * 512 + col * 2) ^ ((rl & 7) << 4);
                    *(short*)((char*)ldsF + byte) = f2bs(v);
                }
        }
    }
    __syncthreads();
    // ---- phase 2: ff2 + final BN (residual from ldsH) ----
    {
        const int m0 = (wid >> 1) * 32;
        const int n0 = (wid & 1) * 64;
        f32x4 acc[2][4] = {};
        const short* Wp = wbf + 180224 + (size_t)(n0 + lrow) * 256 + lk;
        #pragma unroll
        for (int ks = 0; ks < 256; ks += 32) {
            bf8 af[2], wf[4];
            #pragma unroll
            for (int i = 0; i < 2; ++i) {
                int row = m0 + lrow + i * 16;
                int byte = (row * 512 + (ks + lk) * 2) ^ ((row & 7) << 4);
                af[i] = *(const bf8*)((const char*)ldsF + byte);
            }
            #pragma unroll
            for (int j = 0; j < 4; ++j) wf[j] = *(const bf8*)(Wp + (size_t)j * 16 * 256 + ks);
            #pragma unroll
            for (int i = 0; i < 2; ++i)
                #pragma unroll
                for (int j = 0; j < 4; ++j)
                    acc[i][j] = __builtin_amdgcn_mfma_f32_16x16x32_bf16(af[i], wf[j], acc[i][j], 0, 0, 0);
        }
        #pragma unroll
        for (int j = 0; j < 4; ++j) {
            int col = n0 + j * 16 + lrow;
            float bc = b2[col];
            float gsc = g2[col] * rs;
            float bsc = b2g[col];
            #pragma unroll
            for (int i = 0; i < 2; ++i)
                #pragma unroll
                for (int r = 0; r < 4; ++r) {
                    int rl = m0 + i * 16 + rbase + r;
                    int hbyte = (rl * 256 + col * 2) ^ ((rl & 7) << 4);
                    float hres = bs1f(*(const short*)((const char*)ldsH + hbyte));
                    float v = acc[i][j][r] + bc;
                    out[(size_t)(my * 64 + rl) * 128 + col] = (hres + v) * gsc + bsc;
                }
        }
    }
}

// ---------------------------------------------------------------------------
extern "C" void kernel_launch(void* const* d_in, const int* in_sizes, int n_in,
                              void* d_out, int out_size, void* d_ws, size_t ws_size,
                              hipStream_t stream)
{
    (void)in_sizes; (void)n_in; (void)out_size; (void)ws_size;

    const float* x    = (const float*)d_in[0];
    const int*   ei   = (const int*)d_in[1];
    const float* Wres = (const float*)d_in[3];
    const float* bres = (const float*)d_in[4];
    const float* Wk   = (const float*)d_in[5];
    const float* bk   = (const float*)d_in[6];
    const float* Wq   = (const float*)d_in[7];
    const float* bq   = (const float*)d_in[8];
    const float* Wv   = (const float*)d_in[9];
    const float* bv   = (const float*)d_in[10];
    const float* Wsk  = (const float*)d_in[11];
    const float* bsk  = (const float*)d_in[12];
    const float* g1l  = (const float*)d_in[13];
    const float* b1l  = (const float*)d_in[14];
    const float* g1a  = (const float*)d_in[15];
    const float* b1a  = (const float*)d_in[16];
    const float* Win  = (const float*)d_in[17];
    const float* bin  = (const float*)d_in[18];
    const float* Wout = (const float*)d_in[19];
    const float* bout = (const float*)d_in[20];
    const float* W1   = (const float*)d_in[21];
    const float* b1   = (const float*)d_in[22];
    const float* W2   = (const float*)d_in[23];
    const float* b2   = (const float*)d_in[24];
    const float* g2   = (const float*)d_in[25];
    const float* b2g  = (const float*)d_in[26];
    float* out = (float*)d_out;

    float* ws = (float*)d_ws;
    // ----- workspace layout (float-slot offsets), lifetimes k0..k6 -----
    short* hin1b = (short*)ws;                        // [0,0.5NM)  w:k2 r:k3,k4,k6
    short* kbv   = (short*)(ws + NM / 2);             // [0.5NM,NM) w:k2 r:k4
    short* qvb   = (short*)(ws + NM);                 // [NM,2NM)   w:k2 r:k4 (q,v ilv)
    short* skipb = (short*)(ws + 2 * NM);             // [2NM,2.5NM) w:k2 r:k4
    short* xb    = (short*)(ws + 2 * NM + NM / 2);    // [2.5NM,3NM) w:k1 r:k2
    short* qkvb  = (short*)(ws + 3 * NM);             // [3NM,4.5NM) w:k3 r:k5
    short* hlocb = (short*)(ws + 4 * NM + NM / 2);    // [4.5NM,5NM) w:k4 r:k6
    // slot ints/ushorts overlay [5NM, ...) — dead after k4; ctxb (w:k5) reuses it
    int* deg = (int*)(ws + 5 * NM);                   // [N] w:k0, rmw:k1 r:k4
    unsigned short* slots = (unsigned short*)(deg + N_NODES);  // [N*CAP] w:k1 r:k4
    short* ctxb  = (short*)(ws + 5 * NM);             // [5NM,5.5NM) w:k5 r:k6
    short* wbf   = (short*)(ws + 6 * NM);             // 212992 shorts = 106496 fslots
    float* bcat  = ws + 6 * NM + 106496;              // [640] f32
    // total extent: 6NM + 107136 floats ≈ 101.1 MB

    dim3 blk(256);
    // 1/sqrt(32) * log2(e)  (exp2-domain softmax)
    const float qscale = 0.17677669529663687f * 1.4426950408889634f;

    // 0. zero deg
    zero_deg_kernel<<<dim3(32), blk, 0, stream>>>((int4*)deg);

    // 1. scatter (first) + cvt
    cvt_scatter_kernel<<<dim3(6353), blk, 0, stream>>>(
        x, Wres, Wk, Wq, Wv, Wsk, Win, Wout, W1, W2,
        bres, bk, bq, bv, bsk, ei, xb, wbf, bcat, deg, slots);

    // 2. proj5 GEMM (merged 5 groups)
    proj5_kernel<<<dim3(512), blk, 0, stream>>>(
        xb, wbf, bcat, hin1b, kbv, (unsigned int*)qvb, skipb);

    // 3. in_proj GEMM (merged 3 groups)
    inproj_kernel<<<dim3(512), blk, 0, stream>>>(
        hin1b, wbf, bin, qkvb, qscale);

    // 4. gather + skip + BN (slot lists)
    gather_local_kernel<<<dim3(N_NODES / 4), blk, 0, stream>>>(
        (const unsigned int*)kbv, (const uint2*)qvb, (const unsigned int*)skipb,
        (const unsigned int*)hin1b, deg, slots, g1l, b1l,
        (unsigned int*)hlocb);

    // 5. attention (512 blocks x 512 thr, 2 blocks/CU; trunc P-pack)
    attn_mfma<<<dim3(512), dim3(512), 0, stream>>>(qkvb, ctxb);

    // 6. fused out_proj + combine + FFN + final BN
    outproj_ff_kernel<<<dim3(512), blk, 0, stream>>>(
        ctxb, wbf, bout, hin1b, hlocb, g1a, b1a, b1, b2, g2, b2g, out);
}